// Round 7
// baseline (2065.534 us; speedup 1.0000x reference)
//
#include <hip/hip_runtime.h>
#include <hip/hip_cooperative_groups.h>
#include <math.h>

namespace cg = cooperative_groups;

// ---------------- constants ----------------
#define INV_EPS_L2E 577.0780163555854f   // (1/eps) * log2(e) = 1/(eps*ln2)
#define EPS_LOGN 0.02079441542f          // eps * ln(4096) = -eps*loga
#define EPS_LN2 0.00173286795f           // eps * ln(2)

#define NPTS 4096
#define CHUNK 64
#define NCH 64            // 4096/64
#define CPT 8             // columns per thread (4 packed pairs)
#define COLS_PER_BLK 2048 // 256*CPT
#define NCB 2             // 4096/2048
#define NTILES 768        // 6 q * 64 chunks * 2 col-blocks
#define QSTRIDE (NCH * NPTS)  // 262144 floats per problem in partial arrays

typedef float v2f __attribute__((ext_vector_type(2)));

// accumulator slots (floats) at start of workspace
constexpr int A_SSIMA  = 0;   // [B]
constexpr int A_SSIMB  = 2;   // [B]
constexpr int A_SSIMC  = 4;   // [B]
constexpr int A_CH1    = 6;
constexpr int A_CH2    = 7;
constexpr int A_AUX    = 8;
constexpr int A_INT    = 9;
constexpr int A_LOUT   = 10;  // [B]
constexpr int A_CNT    = 12;  // [B]
constexpr int A_SMOOTH = 14;
constexpr int A_SINK   = 16;  // [6]
constexpr int A_MAX    = 32;  // 8 uint slots (4 fields x B), float-bits

// ---------------- block reduction helpers (blockDim == 256) ----------------
__device__ __forceinline__ float blockSum(float v, int tid) {
#pragma unroll
    for (int o = 32; o; o >>= 1) v += __shfl_down(v, o, 64);
    __shared__ float sh[4];
    __syncthreads();
    if ((tid & 63) == 0) sh[tid >> 6] = v;
    __syncthreads();
    return sh[0] + sh[1] + sh[2] + sh[3];
}

__device__ __forceinline__ float blockMax(float v, int tid) {
#pragma unroll
    for (int o = 32; o; o >>= 1) v = fmaxf(v, __shfl_down(v, o, 64));
    __shared__ float sh[4];
    __syncthreads();
    if ((tid & 63) == 0) sh[tid >> 6] = v;
    __syncthreads();
    return fmaxf(fmaxf(sh[0], sh[1]), fmaxf(sh[2], sh[3]));
}

// ---------------- prep: y_gray, intensity, L_out, mask count ----------------
__global__ __launch_bounds__(256) void egf_prep(const float* __restrict__ y,
                                                const float* __restrict__ pet,
                                                const float* __restrict__ mask,
                                                float* __restrict__ ygray,
                                                float* __restrict__ acc) {
    int b = blockIdx.y;
    int p = blockIdx.x * 256 + threadIdx.x;      // exactly 65536
    float m  = mask[b * 65536 + p];
    float y0 = y[(b * 3 + 0) * 65536 + p];
    float y1 = y[(b * 3 + 1) * 65536 + p];
    float y2 = y[(b * 3 + 2) * 65536 + p];
    float q0 = pet[(b * 3 + 0) * 65536 + p];
    float q1 = pet[(b * 3 + 1) * 65536 + p];
    float q2 = pet[(b * 3 + 2) * 65536 + p];
    ygray[b * 65536 + p] = (y0 + y1 + y2) * (1.0f / 3.0f);
    float d0 = m * y0 - m * q0, d1 = m * y1 - m * q1, d2 = m * y2 - m * q2;
    float inten = d0 * d0 + d1 * d1 + d2 * d2;
    float im = 1.0f - m;
    float o0 = y0 * im, o1 = y1 * im, o2 = y2 * im;
    float lout = o0 * o0 + o1 * o1 + o2 * o2;
    float cnt = (m > 0.1f) ? 1.0f : 0.0f;
    float t;
    t = blockSum(inten, threadIdx.x); if (threadIdx.x == 0) atomicAdd(&acc[A_INT], t);
    t = blockSum(lout,  threadIdx.x); if (threadIdx.x == 0) atomicAdd(&acc[A_LOUT + b], t);
    t = blockSum(cnt,   threadIdx.x); if (threadIdx.x == 0) atomicAdd(&acc[A_CNT + b], t);
}

// ---------------- avgpool2 (y channel-mean, mri) ----------------
__global__ __launch_bounds__(256) void egf_pool(const float* __restrict__ y,
                                                const float* __restrict__ mri,
                                                float* __restrict__ py,
                                                float* __restrict__ pmri) {
    int b = blockIdx.y;
    int po = blockIdx.x * 256 + threadIdx.x;     // exactly 16384
    int i = po >> 7, j = po & 127;
    int p0 = (i * 2) * 256 + j * 2;
    float s = 0.0f;
#pragma unroll
    for (int c = 0; c < 3; c++) {
        const float* ip = y + (b * 3 + c) * 65536;
        s += ip[p0] + ip[p0 + 1] + ip[p0 + 256] + ip[p0 + 257];
    }
    py[b * 16384 + po] = s * (1.0f / 12.0f);
    const float* mp = mri + b * 65536;
    pmri[b * 16384 + po] = (mp[p0] + mp[p0 + 1] + mp[p0 + 256] + mp[p0 + 257]) * 0.25f;
}

// ---------------- sobel magnitude + per-sample max ----------------
__global__ __launch_bounds__(256) void egf_sobel(const float* __restrict__ in,
                                                 float* __restrict__ mag,
                                                 unsigned* __restrict__ mx,
                                                 int H, int logH) {
    int b = blockIdx.y;
    int p = blockIdx.x * 256 + threadIdx.x;
    int HH = H * H;
    const float* ip = in + b * HH;
    int i = p >> logH, j = p & (H - 1);
    auto at = [&](int ii, int jj) -> float {
        return (ii >= 0 && ii < H && jj >= 0 && jj < H) ? ip[(ii << logH) + jj] : 0.0f;
    };
    float a00 = at(i - 1, j - 1), a01 = at(i - 1, j), a02 = at(i - 1, j + 1);
    float a10 = at(i, j - 1),                         a12 = at(i, j + 1);
    float a20 = at(i + 1, j - 1), a21 = at(i + 1, j), a22 = at(i + 1, j + 1);
    float gx = a00 - a02 + 2.0f * a10 - 2.0f * a12 + a20 - a22;
    float gy = a00 + 2.0f * a01 + a02 - a20 - 2.0f * a21 - a22;
    float m = sqrtf(gx * gx + gy * gy + 1e-6f);
    mag[b * HH + p] = m;
    float bm = blockMax(m, threadIdx.x);
    if (threadIdx.x == 0) atomicMax(mx + b, __float_as_uint(bm));
}

// ---------------- charbonnier(+aux) over a normalized sobel pair ----------------
__global__ __launch_bounds__(256) void egf_charb(const float* __restrict__ magA,
                                                 const float* __restrict__ magB,
                                                 const unsigned* __restrict__ mxA,
                                                 const unsigned* __restrict__ mxB,
                                                 const float* __restrict__ ehat,
                                                 float* __restrict__ accC,
                                                 float* __restrict__ accAux,
                                                 int HH) {
    int b = blockIdx.y;
    int p = blockIdx.x * 256 + threadIdx.x;
    float c = 0.0f, au = 0.0f;
    float da = fmaxf(__uint_as_float(mxA[b]), 1e-6f);
    float db = fmaxf(__uint_as_float(mxB[b]), 1e-6f);
    if (p < HH) {
        float sa = magA[b * HH + p] / da;
        float sb = magB[b * HH + p] / db;
        float d = sa - sb;
        c = sqrtf(d * d + 1e-6f);
        if (ehat) au = fabsf(ehat[b * HH + p] - sb);
    }
    float tc = blockSum(c, threadIdx.x);
    if (threadIdx.x == 0) atomicAdd(accC, tc);
    if (ehat) {
        float ta = blockSum(au, threadIdx.x);
        if (threadIdx.x == 0) atomicAdd(accAux, ta);
    }
}

// ---------------- SSIM (11x11 gaussian, VALID -> 246x246), per-b sums ----------------
__global__ __launch_bounds__(256) void egf_ssim(const float* __restrict__ X, int xBS, int xCS,
                                                const float* __restrict__ Y, int yBS, int yCS,
                                                const float* __restrict__ M,
                                                int C_, float* __restrict__ accB) {
    int bc = blockIdx.z; int b = bc / C_; int c = bc - b * C_;
    const float* xp = X + b * xBS + c * xCS;
    const float* yp = Y + b * yBS + c * yCS;
    const float* mp = M ? (M + b * 65536) : nullptr;
    __shared__ float sx[26][27];
    __shared__ float sy[26][27];
    int ti = blockIdx.x * 16, tj = blockIdx.y * 16;
    int tid = threadIdx.y * 16 + threadIdx.x;
    for (int t = tid; t < 26 * 26; t += 256) {
        int li = t / 26, lj = t - li * 26;
        int gi = ti + li, gj = tj + lj;
        float a = 0.0f, bb = 0.0f;
        if (gi < 256 && gj < 256) {
            int p = (gi << 8) + gj;
            float m = mp ? mp[p] : 1.0f;
            a = xp[p] * m; bb = yp[p] * m;
        }
        sx[li][lj] = a; sy[li][lj] = bb;
    }
    __syncthreads();
    float w[11];
    {
        float s = 0.0f;
#pragma unroll
        for (int i = 0; i < 11; i++) { float d = (float)(i - 5); w[i] = expf(-d * d * (1.0f / 4.5f)); s += w[i]; }
        float inv = 1.0f / s;
#pragma unroll
        for (int i = 0; i < 11; i++) w[i] *= inv;
    }
    int oi = ti + threadIdx.y, oj = tj + threadIdx.x;
    float val = 0.0f;
    if (oi < 246 && oj < 246) {
        float mu1 = 0, mu2 = 0, xx = 0, yy = 0, xy = 0;
        for (int di = 0; di < 11; di++) {
            float wi = w[di];
#pragma unroll
            for (int dj = 0; dj < 11; dj++) {
                float ww = wi * w[dj];
                float a  = sx[threadIdx.y + di][threadIdx.x + dj];
                float bb = sy[threadIdx.y + di][threadIdx.x + dj];
                mu1 += ww * a; mu2 += ww * bb;
                xx += ww * a * a; yy += ww * bb * bb; xy += ww * a * bb;
            }
        }
        float s11 = xx - mu1 * mu1, s22 = yy - mu2 * mu2, s12 = xy - mu1 * mu2;
        const float C1 = 1e-4f, C2 = 9e-4f;
        val = ((2.0f * mu1 * mu2 + C1) * (2.0f * s12 + C2)) /
              ((mu1 * mu1 + mu2 * mu2 + C1) * (s11 + s22 + C2));
    }
    float tot = blockSum(val, tid);
    if (tid == 0) atomicAdd(&accB[b], tot);
}

// ---------------- gaussian smooth (9-tap sigma=1, symmetric pad), two passes ----------------
__device__ __forceinline__ int refl256(int i) { return i < 0 ? -1 - i : (i > 255 ? 511 - i : i); }

__device__ __forceinline__ void gauss9(float* w) {
    float s = 0.0f;
#pragma unroll
    for (int t = 0; t < 9; t++) { float d = (float)(t - 4); w[t] = expf(-0.5f * d * d); s += w[t]; }
    float inv = 1.0f / s;
#pragma unroll
    for (int t = 0; t < 9; t++) w[t] *= inv;
}

__global__ __launch_bounds__(256) void egf_smoothV(const float* __restrict__ y, float* __restrict__ tmp) {
    int g = blockIdx.x * 256 + threadIdx.x;      // < 393216
    int bc = g >> 16; int p = g & 65535; int i = p >> 8, j = p & 255;
    float w[9]; gauss9(w);
    const float* ip = y + bc * 65536;
    float s = 0.0f;
#pragma unroll
    for (int t = 0; t < 9; t++) s += w[t] * ip[(refl256(i + t - 4) << 8) + j];
    tmp[g] = s;
}

__global__ __launch_bounds__(256) void egf_smoothH(const float* __restrict__ tmp,
                                                   const float* __restrict__ y,
                                                   float* __restrict__ acc) {
    int g = blockIdx.x * 256 + threadIdx.x;
    int bc = g >> 16; int p = g & 65535; int i = p >> 8, j = p & 255;
    float w[9]; gauss9(w);
    const float* tp = tmp + bc * 65536;
    float s = 0.0f;
#pragma unroll
    for (int t = 0; t < 9; t++) s += w[t] * tp[(i << 8) + refl256(j + t - 4)];
    float d = s - y[g];
    float tt = blockSum(d * d, threadIdx.x);
    if (threadIdx.x == 0) atomicAdd(acc, tt);
}

// ---------------- gather masked point clouds ----------------
__global__ __launch_bounds__(256) void egf_gather(const float* __restrict__ y,
                                                  const float* __restrict__ pet,
                                                  const float* __restrict__ mask,
                                                  const int* __restrict__ idx,
                                                  float4* __restrict__ pts) {
    int t = blockIdx.x * 256 + threadIdx.x;      // < 8192
    int b = t >> 12, j = t & 4095;
    int p = idx[b * 4096 + j];
    float m = mask[b * 65536 + p];
    float a0 = y[(b * 3 + 0) * 65536 + p] * m;
    float a1 = y[(b * 3 + 1) * 65536 + p] * m;
    float a2 = y[(b * 3 + 2) * 65536 + p] * m;
    pts[(b * 2 + 0) * 4096 + j] = make_float4(a0, a1, a2, 0.5f * (a0 * a0 + a1 * a1 + a2 * a2));
    float c0 = pet[(b * 3 + 0) * 65536 + p] * m;
    float c1 = pet[(b * 3 + 1) * 65536 + p] * m;
    float c2 = pet[(b * 3 + 2) * 65536 + p] * m;
    pts[(b * 2 + 1) * 4096 + j] = make_float4(c0, c1, c2, 0.5f * (c0 * c0 + c1 * c1 + c2 * c2));
}

// ---------------- fused combine (staging) helper, NCH=64 ----------------
__device__ __forceinline__ float stageCombine(const float* __restrict__ Pin_m,
                                              const float* __restrict__ Pin_s,
                                              int qbase, int row, int h, int r_local,
                                              float* sm, float* ss, int tid) {
    const float* pm = Pin_m + qbase + h * 16 * NPTS + row;
    const float* ps = Pin_s + qbase + h * 16 * NPTS + row;
    float mv[16], sv[16];
#pragma unroll
    for (int k = 0; k < 16; k++) mv[k] = pm[k * NPTS];
#pragma unroll
    for (int k = 0; k < 16; k++) sv[k] = ps[k * NPTS];
    float m16 = -3.4e38f;
#pragma unroll
    for (int k = 0; k < 16; k++) m16 = fmaxf(m16, mv[k]);
    float s16 = 0.0f;
#pragma unroll
    for (int k = 0; k < 16; k++) s16 += sv[k] * __builtin_amdgcn_exp2f(mv[k] - m16);
    sm[h * 64 + r_local] = m16;
    ss[h * 64 + r_local] = s16;
    __syncthreads();
    float v = 0.0f;
    if (tid < 64) {
        float m0 = sm[tid], m1 = sm[64 + tid], m2 = sm[128 + tid], m3 = sm[192 + tid];
        float M = fmaxf(fmaxf(m0, m1), fmaxf(m2, m3));
        float S = ss[tid]       * __builtin_amdgcn_exp2f(m0 - M) +
                  ss[64 + tid]  * __builtin_amdgcn_exp2f(m1 - M) +
                  ss[128 + tid] * __builtin_amdgcn_exp2f(m2 - M) +
                  ss[192 + tid] * __builtin_amdgcn_exp2f(m3 - M);
        v = EPS_LOGN - EPS_LN2 * (M + log2f(S));
    }
    return v;
}

// ---------------- one half-iteration body (shared by coop + fallback) ----------
__device__ __forceinline__ void sinkTileBody(const float4* __restrict__ pts,
                                             const float* __restrict__ Pin_m,
                                             const float* __restrict__ Pin_s,
                                             float* __restrict__ Pout_m,
                                             float* __restrict__ Pout_s,
                                             int dir, int init, int tile,
                                             float4* srow, float* sm, float* ss, int tid) {
    int q = tile >> 7;
    int r = tile & 127;
    int chunk = r >> 1;
    int cb = r & 1;
    int b = q / 3, t = q - b * 3;
    int xsel = (t == 2) ? 1 : 0;
    int ysel = (t == 1) ? 0 : 1;
    const float4* rowP = pts + (b * 2 + (dir ? ysel : xsel)) * NPTS;
    const float4* colP = pts + (b * 2 + (dir ? xsel : ysel)) * NPTS;
    int r_local = tid & 63, h = tid >> 6;
    int row = chunk * CHUNK + r_local;
    int col0 = cb * COLS_PER_BLK + tid;

    float v = 0.0f;
    if (!init)
        v = stageCombine(Pin_m, Pin_s, q * QSTRIDE, row, h, r_local, sm, ss, tid);
    if (tid < 64) {
        float4 pp = rowP[row];
        srow[tid] = make_float4(pp.x * INV_EPS_L2E, pp.y * INV_EPS_L2E,
                                pp.z * INV_EPS_L2E, (v - pp.w) * INV_EPS_L2E);
    }
    __syncthreads();

    v2f cx[4], cy[4], cz[4], cw[4];
#pragma unroll
    for (int p = 0; p < 4; p++) {
        float4 c0 = colP[col0 + (2 * p) * 256];
        float4 c1 = colP[col0 + (2 * p + 1) * 256];
        cx[p] = (v2f){c0.x, c1.x};
        cy[p] = (v2f){c0.y, c1.y};
        cz[p] = (v2f){c0.z, c1.z};
        cw[p] = (v2f){c0.w * INV_EPS_L2E, c1.w * INV_EPS_L2E};
    }
    v2f mx[4];
#pragma unroll
    for (int p = 0; p < 4; p++) mx[p] = -3.4e38f;
#pragma unroll 4
    for (int rr = 0; rr < CHUNK; rr++) {
        float4 rp = srow[rr];
        v2f rx = rp.x, ry = rp.y, rz = rp.z, rw = rp.w;
#pragma unroll
        for (int p = 0; p < 4; p++) {
            v2f e = rw;
            e = __builtin_elementwise_fma(rx, cx[p], e);
            e = __builtin_elementwise_fma(ry, cy[p], e);
            e = __builtin_elementwise_fma(rz, cz[p], e);
            mx[p] = __builtin_elementwise_max(mx[p], e);
        }
    }
    v2f sa[4];
#pragma unroll
    for (int p = 0; p < 4; p++) sa[p] = 0.0f;
#pragma unroll 4
    for (int rr = 0; rr < CHUNK; rr++) {
        float4 rp = srow[rr];
        v2f rx = rp.x, ry = rp.y, rz = rp.z, rw = rp.w;
#pragma unroll
        for (int p = 0; p < 4; p++) {
            v2f e = rw - mx[p];
            e = __builtin_elementwise_fma(rx, cx[p], e);
            e = __builtin_elementwise_fma(ry, cy[p], e);
            e = __builtin_elementwise_fma(rz, cz[p], e);
            v2f ex;
            ex.x = __builtin_amdgcn_exp2f(e.x);
            ex.y = __builtin_amdgcn_exp2f(e.y);
            sa[p] += ex;
        }
    }
    float* om = Pout_m + q * QSTRIDE + chunk * NPTS;
    float* os = Pout_s + q * QSTRIDE + chunk * NPTS;
#pragma unroll
    for (int p = 0; p < 4; p++) {
        v2f mstore = mx[p] - cw[p];
        om[col0 + (2 * p) * 256]     = mstore.x;
        om[col0 + (2 * p + 1) * 256] = mstore.y;
        os[col0 + (2 * p) * 256]     = sa[p].x;
        os[col0 + (2 * p + 1) * 256] = sa[p].y;
    }
    __syncthreads();   // protect srow/sm/ss reuse by the next tile / next half
}

// ---------------- fused cooperative sinkhorn: all 22 halves in one kernel ----
__global__ __launch_bounds__(256, 3) void egf_sink_coop(const float4* __restrict__ pts,
                                                        float* __restrict__ Pf_m,
                                                        float* __restrict__ Pf_s,
                                                        float* __restrict__ Pg_m,
                                                        float* __restrict__ Pg_s,
                                                        int ntiles) {
    cg::grid_group grid = cg::this_grid();
    __shared__ float4 srow[CHUNK];
    __shared__ float sm[256], ss[256];
    int tid = threadIdx.x;
    int nb = gridDim.x;

    for (int hh = 0; hh < 22; hh++) {
        int dir = hh & 1;
        const float* Pin_m = dir ? Pg_m : Pf_m;
        const float* Pin_s = dir ? Pg_s : Pf_s;
        float* Pout_m = dir ? Pf_m : Pg_m;
        float* Pout_s = dir ? Pf_s : Pg_s;
        for (int tile = blockIdx.x; tile < ntiles; tile += nb)
            sinkTileBody(pts, Pin_m, Pin_s, Pout_m, Pout_s, dir, hh == 0, tile,
                         srow, sm, ss, tid);
        if (hh < 21) grid.sync();
    }
}

// ---------------- fallback per-launch half (R5-proven) ----------------
__global__ __launch_bounds__(256) void egf_sink_half5(const float4* __restrict__ pts,
                                                      const float* __restrict__ Pin_m,
                                                      const float* __restrict__ Pin_s,
                                                      float* __restrict__ Pout_m,
                                                      float* __restrict__ Pout_s,
                                                      int dir, int init) {
    __shared__ float4 srow[CHUNK];
    __shared__ float sm[256], ss[256];
    int tile = blockIdx.z * 128 + blockIdx.y * 2 + blockIdx.x;  // q*128 + chunk*2 + cb
    sinkTileBody(pts, Pin_m, Pin_s, Pout_m, Pout_s, dir, init, tile,
                 srow, sm, ss, (int)threadIdx.x);
}

// ---------------- sinkhorn value: f.mean() + g.mean() per problem ----------------
__global__ __launch_bounds__(256) void egf_sink_val5(const float* __restrict__ Pf_m,
                                                     const float* __restrict__ Pf_s,
                                                     const float* __restrict__ Pg_m,
                                                     const float* __restrict__ Pg_s,
                                                     float* __restrict__ acc) {
    int q = blockIdx.y;
    int side = blockIdx.x >> 6;
    int chunk = blockIdx.x & 63;
    const float* Pm = side ? Pg_m : Pf_m;
    const float* Ps = side ? Pg_s : Pf_s;
    __shared__ float sm[256], ss[256];
    int tid = threadIdx.x;
    int r_local = tid & 63, h = tid >> 6;
    int row = chunk * CHUNK + r_local;
    float v = stageCombine(Pm, Ps, q * QSTRIDE, row, h, r_local, sm, ss, tid);
    float tot = blockSum(v, tid);
    if (tid == 0) atomicAdd(&acc[A_SINK + q], tot * (1.0f / 4096.0f));
}

// ---------------- final scalar assembly ----------------
__global__ void egf_finalize(const float* __restrict__ acc, float* __restrict__ out) {
    if (threadIdx.x != 0 || blockIdx.x != 0) return;
    const float AREA = 246.0f * 246.0f;
    float ssim_m = 1.0f - (acc[A_SSIMA] + acc[A_SSIMA + 1]) / (2.0f * AREA);
    float ssim_p = 1.0f - (acc[A_SSIMB] + acc[A_SSIMB + 1]) / (2.0f * 3.0f * AREA);
    float g_cons = acc[A_CH1] / (2.0f * 65536.0f) + acc[A_CH2] / (2.0f * 16384.0f);
    float aux = acc[A_AUX] / (2.0f * 65536.0f);
    float inc0 = (acc[A_CNT]     >= 31.5f) ? 1.0f : 0.0f;
    float inc1 = (acc[A_CNT + 1] >= 31.5f) ? 1.0f : 0.0f;
    const float* v = acc + A_SINK;
    float Lt = (inc0 * (v[0] - 0.5f * v[1] - 0.5f * v[2]) +
                inc1 * (v[3] - 0.5f * v[4] - 0.5f * v[5])) * 0.5f;
    float Lo = (inc0 * acc[A_LOUT] + inc1 * acc[A_LOUT + 1]) / (3.0f * 65536.0f) * 0.5f;
    float Ls = (inc0 * (1.0f - acc[A_SSIMC] / (3.0f * AREA)) +
                inc1 * (1.0f - acc[A_SSIMC + 1] / (3.0f * AREA))) * 0.5f;
    float Li = 2.5f * acc[A_INT] / (2.0f * 3.0f * 65536.0f);
    float Lsm = acc[A_SMOOTH] / (2.0f * 3.0f * 65536.0f);
    float total = 0.8f * Lt + 0.3f * Lo + 0.5f * Ls + Li + 0.2f * Lsm;
    out[0] = total; out[1] = ssim_m; out[2] = ssim_p; out[3] = g_cons; out[4] = aux;
}

// ---------------- host launch ----------------
extern "C" void kernel_launch(void* const* d_in, const int* in_sizes, int n_in,
                              void* d_out, int out_size, void* d_ws, size_t ws_size,
                              hipStream_t stream) {
    const float* y    = (const float*)d_in[0];
    const float* mri  = (const float*)d_in[1];
    const float* pet  = (const float*)d_in[2];
    const float* mask = (const float*)d_in[3];
    const float* ehat = (const float*)d_in[4];
    const int*   idx  = (const int*)d_in[5];
    float* out = (float*)d_out;
    float* ws  = (float*)d_ws;

    float* acc   = ws;                    // 64 floats
    float4* pts  = (float4*)(ws + 64);    // 4*4096 float4 = 65536 floats
    float* base  = ws + 64 + 65536;

    // sinkhorn partials: 4 planes of 6*64*4096 = 1572864 floats each
    float* Pf_m = base;
    float* Pf_s = base + QSTRIDE * 6;
    float* Pg_m = base + 2 * QSTRIDE * 6;
    float* Pg_s = base + 3 * QSTRIDE * 6;
    float* ibase = base + 4 * QSTRIDE * 6;

    // image scratch
    float* ygray    = ibase;              // 131072
    float* py       = ygray + 131072;     // 32768
    float* pmri     = py + 32768;         // 32768
    float* mag_yg   = pmri + 32768;       // 131072
    float* mag_mri  = mag_yg + 131072;    // 131072
    float* mag_py   = mag_mri + 131072;   // 32768
    float* mag_pmri = mag_py + 32768;     // 32768
    float* tmp      = mag_pmri + 32768;   // 393216

    hipMemsetAsync(acc, 0, 64 * sizeof(float), stream);

    unsigned* mx = (unsigned*)(acc + A_MAX);

    egf_prep<<<dim3(256, 2), 256, 0, stream>>>(y, pet, mask, ygray, acc);
    egf_pool<<<dim3(64, 2), 256, 0, stream>>>(y, mri, py, pmri);
    egf_sobel<<<dim3(256, 2), 256, 0, stream>>>(ygray, mag_yg, mx + 0, 256, 8);
    egf_sobel<<<dim3(256, 2), 256, 0, stream>>>(mri, mag_mri, mx + 2, 256, 8);
    egf_sobel<<<dim3(64, 2), 256, 0, stream>>>(py, mag_py, mx + 4, 128, 7);
    egf_sobel<<<dim3(64, 2), 256, 0, stream>>>(pmri, mag_pmri, mx + 6, 128, 7);
    egf_charb<<<dim3(256, 2), 256, 0, stream>>>(mag_yg, mag_mri, mx + 0, mx + 2, ehat,
                                                acc + A_CH1, acc + A_AUX, 65536);
    egf_charb<<<dim3(64, 2), 256, 0, stream>>>(mag_py, mag_pmri, mx + 4, mx + 6, nullptr,
                                               acc + A_CH2, nullptr, 16384);
    egf_ssim<<<dim3(16, 16, 2), dim3(16, 16), 0, stream>>>(ygray, 65536, 0, mri, 65536, 0,
                                                           nullptr, 1, acc + A_SSIMA);
    egf_ssim<<<dim3(16, 16, 6), dim3(16, 16), 0, stream>>>(y, 196608, 65536, pet, 196608, 65536,
                                                           nullptr, 3, acc + A_SSIMB);
    egf_ssim<<<dim3(16, 16, 6), dim3(16, 16), 0, stream>>>(y, 196608, 65536, mri, 65536, 0,
                                                           mask, 3, acc + A_SSIMC);
    egf_smoothV<<<1536, 256, 0, stream>>>(y, tmp);
    egf_smoothH<<<1536, 256, 0, stream>>>(tmp, y, acc + A_SMOOTH);
    egf_gather<<<32, 256, 0, stream>>>(y, pet, mask, idx, pts);

    // ---- sinkhorn: cooperative if possible, else 22-launch fallback ----
    bool coop_done = false;
    {
        int perCU = 0, numCU = 0, dev = 0;
        hipGetDevice(&dev);
        hipDeviceGetAttribute(&numCU, hipDeviceAttributeMultiprocessorCount, dev);
        hipError_t oe = hipOccupancyMaxActiveBlocksPerMultiprocessor(&perCU, egf_sink_coop, 256, 0);
        int maxBlocks = (oe == hipSuccess) ? perCU * numCU : 0;
        int grid = maxBlocks < NTILES ? maxBlocks : NTILES;
        if (grid > 0) {
            const float4* pts_c = (const float4*)pts;
            int ntiles = NTILES;
            void* args[] = {(void*)&pts_c, (void*)&Pf_m, (void*)&Pf_s,
                            (void*)&Pg_m, (void*)&Pg_s, (void*)&ntiles};
            hipError_t le = hipLaunchCooperativeKernel((void*)egf_sink_coop, dim3(grid),
                                                       dim3(256), args, 0, stream);
            coop_done = (le == hipSuccess);
        }
    }
    if (!coop_done) {
        dim3 sgrid(NCB, NCH, 6);
        for (int it = 0; it < 11; ++it) {
            egf_sink_half5<<<sgrid, 256, 0, stream>>>(pts, Pf_m, Pf_s, Pg_m, Pg_s, 0, it == 0 ? 1 : 0);
            egf_sink_half5<<<sgrid, 256, 0, stream>>>(pts, Pg_m, Pg_s, Pf_m, Pf_s, 1, 0);
        }
    }
    egf_sink_val5<<<dim3(128, 6), 256, 0, stream>>>(Pf_m, Pf_s, Pg_m, Pg_s, acc);
    egf_finalize<<<1, 64, 0, stream>>>(acc, out);
}

// Round 8
// 963.483 us; speedup vs baseline: 2.1438x; 2.1438x over previous
//
#include <hip/hip_runtime.h>
#include <math.h>

// ---------------- constants ----------------
#define INV_EPS_L2E 577.0780163555854f   // (1/eps) * log2(e) = 1/(eps*ln2)
#define EPS_LOGN 0.02079441542f          // eps * ln(4096) = -eps*loga
#define EPS_LN2 0.00173286795f           // eps * ln(2)

#define NPTS 4096
#define CHUNK 32
#define NCH 128           // 4096/32
#define CPT 8             // columns per thread (4 packed pairs)
#define COLS_PER_BLK 2048 // 256*CPT
#define NCB 2             // 4096/2048
#define QSTRIDE (NCH * NPTS)  // float2 elements per problem in partial arrays

typedef float v2f __attribute__((ext_vector_type(2)));

// accumulator slots (floats) at start of workspace
constexpr int A_SSIMA  = 0;   // [B]
constexpr int A_SSIMB  = 2;   // [B]
constexpr int A_SSIMC  = 4;   // [B]
constexpr int A_CH1    = 6;
constexpr int A_CH2    = 7;
constexpr int A_AUX    = 8;
constexpr int A_INT    = 9;
constexpr int A_LOUT   = 10;  // [B]
constexpr int A_CNT    = 12;  // [B]
constexpr int A_SMOOTH = 14;
constexpr int A_SINK   = 16;  // [6]
constexpr int A_MAX    = 32;  // 8 uint slots (4 fields x B), float-bits

// ---------------- block reduction helpers (blockDim == 256) ----------------
__device__ __forceinline__ float blockSum(float v, int tid) {
#pragma unroll
    for (int o = 32; o; o >>= 1) v += __shfl_down(v, o, 64);
    __shared__ float sh[4];
    __syncthreads();
    if ((tid & 63) == 0) sh[tid >> 6] = v;
    __syncthreads();
    return sh[0] + sh[1] + sh[2] + sh[3];
}

__device__ __forceinline__ float blockMax(float v, int tid) {
#pragma unroll
    for (int o = 32; o; o >>= 1) v = fmaxf(v, __shfl_down(v, o, 64));
    __shared__ float sh[4];
    __syncthreads();
    if ((tid & 63) == 0) sh[tid >> 6] = v;
    __syncthreads();
    return fmaxf(fmaxf(sh[0], sh[1]), fmaxf(sh[2], sh[3]));
}

// ---------------- prep: y_gray, intensity, L_out, mask count ----------------
__global__ __launch_bounds__(256) void egf_prep(const float* __restrict__ y,
                                                const float* __restrict__ pet,
                                                const float* __restrict__ mask,
                                                float* __restrict__ ygray,
                                                float* __restrict__ acc) {
    int b = blockIdx.y;
    int p = blockIdx.x * 256 + threadIdx.x;      // exactly 65536
    float m  = mask[b * 65536 + p];
    float y0 = y[(b * 3 + 0) * 65536 + p];
    float y1 = y[(b * 3 + 1) * 65536 + p];
    float y2 = y[(b * 3 + 2) * 65536 + p];
    float q0 = pet[(b * 3 + 0) * 65536 + p];
    float q1 = pet[(b * 3 + 1) * 65536 + p];
    float q2 = pet[(b * 3 + 2) * 65536 + p];
    ygray[b * 65536 + p] = (y0 + y1 + y2) * (1.0f / 3.0f);
    float d0 = m * y0 - m * q0, d1 = m * y1 - m * q1, d2 = m * y2 - m * q2;
    float inten = d0 * d0 + d1 * d1 + d2 * d2;
    float im = 1.0f - m;
    float o0 = y0 * im, o1 = y1 * im, o2 = y2 * im;
    float lout = o0 * o0 + o1 * o1 + o2 * o2;
    float cnt = (m > 0.1f) ? 1.0f : 0.0f;
    float t;
    t = blockSum(inten, threadIdx.x); if (threadIdx.x == 0) atomicAdd(&acc[A_INT], t);
    t = blockSum(lout,  threadIdx.x); if (threadIdx.x == 0) atomicAdd(&acc[A_LOUT + b], t);
    t = blockSum(cnt,   threadIdx.x); if (threadIdx.x == 0) atomicAdd(&acc[A_CNT + b], t);
}

// ---------------- avgpool2 (y channel-mean, mri) ----------------
__global__ __launch_bounds__(256) void egf_pool(const float* __restrict__ y,
                                                const float* __restrict__ mri,
                                                float* __restrict__ py,
                                                float* __restrict__ pmri) {
    int b = blockIdx.y;
    int po = blockIdx.x * 256 + threadIdx.x;     // exactly 16384
    int i = po >> 7, j = po & 127;
    int p0 = (i * 2) * 256 + j * 2;
    float s = 0.0f;
#pragma unroll
    for (int c = 0; c < 3; c++) {
        const float* ip = y + (b * 3 + c) * 65536;
        s += ip[p0] + ip[p0 + 1] + ip[p0 + 256] + ip[p0 + 257];
    }
    py[b * 16384 + po] = s * (1.0f / 12.0f);
    const float* mp = mri + b * 65536;
    pmri[b * 16384 + po] = (mp[p0] + mp[p0 + 1] + mp[p0 + 256] + mp[p0 + 257]) * 0.25f;
}

// ---------------- sobel magnitude + per-sample max ----------------
__global__ __launch_bounds__(256) void egf_sobel(const float* __restrict__ in,
                                                 float* __restrict__ mag,
                                                 unsigned* __restrict__ mx,
                                                 int H, int logH) {
    int b = blockIdx.y;
    int p = blockIdx.x * 256 + threadIdx.x;
    int HH = H * H;
    const float* ip = in + b * HH;
    int i = p >> logH, j = p & (H - 1);
    auto at = [&](int ii, int jj) -> float {
        return (ii >= 0 && ii < H && jj >= 0 && jj < H) ? ip[(ii << logH) + jj] : 0.0f;
    };
    float a00 = at(i - 1, j - 1), a01 = at(i - 1, j), a02 = at(i - 1, j + 1);
    float a10 = at(i, j - 1),                         a12 = at(i, j + 1);
    float a20 = at(i + 1, j - 1), a21 = at(i + 1, j), a22 = at(i + 1, j + 1);
    float gx = a00 - a02 + 2.0f * a10 - 2.0f * a12 + a20 - a22;
    float gy = a00 + 2.0f * a01 + a02 - a20 - 2.0f * a21 - a22;
    float m = sqrtf(gx * gx + gy * gy + 1e-6f);
    mag[b * HH + p] = m;
    float bm = blockMax(m, threadIdx.x);
    if (threadIdx.x == 0) atomicMax(mx + b, __float_as_uint(bm));
}

// ---------------- charbonnier(+aux) over a normalized sobel pair ----------------
__global__ __launch_bounds__(256) void egf_charb(const float* __restrict__ magA,
                                                 const float* __restrict__ magB,
                                                 const unsigned* __restrict__ mxA,
                                                 const unsigned* __restrict__ mxB,
                                                 const float* __restrict__ ehat,
                                                 float* __restrict__ accC,
                                                 float* __restrict__ accAux,
                                                 int HH) {
    int b = blockIdx.y;
    int p = blockIdx.x * 256 + threadIdx.x;
    float c = 0.0f, au = 0.0f;
    float da = fmaxf(__uint_as_float(mxA[b]), 1e-6f);
    float db = fmaxf(__uint_as_float(mxB[b]), 1e-6f);
    if (p < HH) {
        float sa = magA[b * HH + p] / da;
        float sb = magB[b * HH + p] / db;
        float d = sa - sb;
        c = sqrtf(d * d + 1e-6f);
        if (ehat) au = fabsf(ehat[b * HH + p] - sb);
    }
    float tc = blockSum(c, threadIdx.x);
    if (threadIdx.x == 0) atomicAdd(accC, tc);
    if (ehat) {
        float ta = blockSum(au, threadIdx.x);
        if (threadIdx.x == 0) atomicAdd(accAux, ta);
    }
}

// ---------------- SSIM (11x11 gaussian, VALID -> 246x246), per-b sums ----------------
__global__ __launch_bounds__(256) void egf_ssim(const float* __restrict__ X, int xBS, int xCS,
                                                const float* __restrict__ Y, int yBS, int yCS,
                                                const float* __restrict__ M,
                                                int C_, float* __restrict__ accB) {
    int bc = blockIdx.z; int b = bc / C_; int c = bc - b * C_;
    const float* xp = X + b * xBS + c * xCS;
    const float* yp = Y + b * yBS + c * yCS;
    const float* mp = M ? (M + b * 65536) : nullptr;
    __shared__ float sx[26][27];
    __shared__ float sy[26][27];
    int ti = blockIdx.x * 16, tj = blockIdx.y * 16;
    int tid = threadIdx.y * 16 + threadIdx.x;
    for (int t = tid; t < 26 * 26; t += 256) {
        int li = t / 26, lj = t - li * 26;
        int gi = ti + li, gj = tj + lj;
        float a = 0.0f, bb = 0.0f;
        if (gi < 256 && gj < 256) {
            int p = (gi << 8) + gj;
            float m = mp ? mp[p] : 1.0f;
            a = xp[p] * m; bb = yp[p] * m;
        }
        sx[li][lj] = a; sy[li][lj] = bb;
    }
    __syncthreads();
    float w[11];
    {
        float s = 0.0f;
#pragma unroll
        for (int i = 0; i < 11; i++) { float d = (float)(i - 5); w[i] = expf(-d * d * (1.0f / 4.5f)); s += w[i]; }
        float inv = 1.0f / s;
#pragma unroll
        for (int i = 0; i < 11; i++) w[i] *= inv;
    }
    int oi = ti + threadIdx.y, oj = tj + threadIdx.x;
    float val = 0.0f;
    if (oi < 246 && oj < 246) {
        float mu1 = 0, mu2 = 0, xx = 0, yy = 0, xy = 0;
        for (int di = 0; di < 11; di++) {
            float wi = w[di];
#pragma unroll
            for (int dj = 0; dj < 11; dj++) {
                float ww = wi * w[dj];
                float a  = sx[threadIdx.y + di][threadIdx.x + dj];
                float bb = sy[threadIdx.y + di][threadIdx.x + dj];
                mu1 += ww * a; mu2 += ww * bb;
                xx += ww * a * a; yy += ww * bb * bb; xy += ww * a * bb;
            }
        }
        float s11 = xx - mu1 * mu1, s22 = yy - mu2 * mu2, s12 = xy - mu1 * mu2;
        const float C1 = 1e-4f, C2 = 9e-4f;
        val = ((2.0f * mu1 * mu2 + C1) * (2.0f * s12 + C2)) /
              ((mu1 * mu1 + mu2 * mu2 + C1) * (s11 + s22 + C2));
    }
    float tot = blockSum(val, tid);
    if (tid == 0) atomicAdd(&accB[b], tot);
}

// ---------------- gaussian smooth (9-tap sigma=1, symmetric pad), two passes ----------------
__device__ __forceinline__ int refl256(int i) { return i < 0 ? -1 - i : (i > 255 ? 511 - i : i); }

__device__ __forceinline__ void gauss9(float* w) {
    float s = 0.0f;
#pragma unroll
    for (int t = 0; t < 9; t++) { float d = (float)(t - 4); w[t] = expf(-0.5f * d * d); s += w[t]; }
    float inv = 1.0f / s;
#pragma unroll
    for (int t = 0; t < 9; t++) w[t] *= inv;
}

__global__ __launch_bounds__(256) void egf_smoothV(const float* __restrict__ y, float* __restrict__ tmp) {
    int g = blockIdx.x * 256 + threadIdx.x;      // < 393216
    int bc = g >> 16; int p = g & 65535; int i = p >> 8, j = p & 255;
    float w[9]; gauss9(w);
    const float* ip = y + bc * 65536;
    float s = 0.0f;
#pragma unroll
    for (int t = 0; t < 9; t++) s += w[t] * ip[(refl256(i + t - 4) << 8) + j];
    tmp[g] = s;
}

__global__ __launch_bounds__(256) void egf_smoothH(const float* __restrict__ tmp,
                                                   const float* __restrict__ y,
                                                   float* __restrict__ acc) {
    int g = blockIdx.x * 256 + threadIdx.x;
    int bc = g >> 16; int p = g & 65535; int i = p >> 8, j = p & 255;
    float w[9]; gauss9(w);
    const float* tp = tmp + bc * 65536;
    float s = 0.0f;
#pragma unroll
    for (int t = 0; t < 9; t++) s += w[t] * tp[(i << 8) + refl256(j + t - 4)];
    float d = s - y[g];
    float tt = blockSum(d * d, threadIdx.x);
    if (threadIdx.x == 0) atomicAdd(acc, tt);
}

// ---------------- gather masked point clouds ----------------
__global__ __launch_bounds__(256) void egf_gather(const float* __restrict__ y,
                                                  const float* __restrict__ pet,
                                                  const float* __restrict__ mask,
                                                  const int* __restrict__ idx,
                                                  float4* __restrict__ pts) {
    int t = blockIdx.x * 256 + threadIdx.x;      // < 8192
    int b = t >> 12, j = t & 4095;
    int p = idx[b * 4096 + j];
    float m = mask[b * 65536 + p];
    float a0 = y[(b * 3 + 0) * 65536 + p] * m;
    float a1 = y[(b * 3 + 1) * 65536 + p] * m;
    float a2 = y[(b * 3 + 2) * 65536 + p] * m;
    pts[(b * 2 + 0) * 4096 + j] = make_float4(a0, a1, a2, 0.5f * (a0 * a0 + a1 * a1 + a2 * a2));
    float c0 = pet[(b * 3 + 0) * 65536 + p] * m;
    float c1 = pet[(b * 3 + 1) * 65536 + p] * m;
    float c2 = pet[(b * 3 + 2) * 65536 + p] * m;
    pts[(b * 2 + 1) * 4096 + j] = make_float4(c0, c1, c2, 0.5f * (c0 * c0 + c1 * c1 + c2 * c2));
}

// ---------------- fused combine (staging) helper, NCH=128, float2 partials ----
// 8 threads per row (h = tid>>5), 16 chunk-partials each; coalesced float2 loads
// (consecutive rows in consecutive lanes). Returns potential v for tid<32.
__device__ __forceinline__ float stageCombine(const float2* __restrict__ Pin,
                                              int qbase, int row, int h,
                                              float* sm, float* ss, int tid) {
    const float2* p = Pin + qbase + (h * 16) * NPTS + row;
    float2 t[16];
#pragma unroll
    for (int k = 0; k < 16; k++) t[k] = p[k * NPTS];
    float m16 = -3.4e38f;
#pragma unroll
    for (int k = 0; k < 16; k++) m16 = fmaxf(m16, t[k].x);
    float s16 = 0.0f;
#pragma unroll
    for (int k = 0; k < 16; k++) s16 += t[k].y * __builtin_amdgcn_exp2f(t[k].x - m16);
    sm[tid] = m16;      // layout [h][r_local] == tid
    ss[tid] = s16;
    __syncthreads();
    float v = 0.0f;
    if (tid < 32) {
        float M = -3.4e38f;
        float mj[8];
#pragma unroll
        for (int j = 0; j < 8; j++) { mj[j] = sm[j * 32 + tid]; M = fmaxf(M, mj[j]); }
        float S = 0.0f;
#pragma unroll
        for (int j = 0; j < 8; j++)
            S += ss[j * 32 + tid] * __builtin_amdgcn_exp2f(mj[j] - M);
        v = EPS_LOGN - EPS_LN2 * (M + log2f(S));
    }
    return v;
}

// ---------------- sinkhorn half update: CHUNK=32, CPT=8, float2 partials ----
// dir=0: rows = X side (f potentials from Pin), cols = Y -> writes g partials.
// dir=1: rows = Y side, cols = X -> writes f partials.
// log2-domain: stored partial m = max_r(a_r + dot) - b_c; b_c cancels in pass 2.
__global__ __launch_bounds__(256, 6) void egf_sink_half6(const float4* __restrict__ pts,
                                                         const float2* __restrict__ Pin,
                                                         float2* __restrict__ Pout,
                                                         int dir, int init) {
    int q = blockIdx.z; int b = q / 3, t = q - b * 3;
    int xsel = (t == 2) ? 1 : 0;
    int ysel = (t == 1) ? 0 : 1;
    const float4* rowP = pts + (b * 2 + (dir ? ysel : xsel)) * NPTS;
    const float4* colP = pts + (b * 2 + (dir ? xsel : ysel)) * NPTS;

    __shared__ float4 srow[CHUNK];
    __shared__ float sm[256], ss[256];
    int tid = threadIdx.x;
    int chunk = blockIdx.y;
    int r_local = tid & 31, h = tid >> 5;
    int row = chunk * CHUNK + r_local;

    float v = 0.0f;
    if (!init)
        v = stageCombine(Pin, q * QSTRIDE, row, h, sm, ss, tid);
    if (tid < 32) {
        float4 pp = rowP[row];
        srow[tid] = make_float4(pp.x * INV_EPS_L2E, pp.y * INV_EPS_L2E,
                                pp.z * INV_EPS_L2E, (v - pp.w) * INV_EPS_L2E);
    }
    __syncthreads();

    int col0 = blockIdx.x * COLS_PER_BLK + tid;
    v2f cx[4], cy[4], cz[4], cw[4];
#pragma unroll
    for (int p = 0; p < 4; p++) {
        float4 c0 = colP[col0 + (2 * p) * 256];
        float4 c1 = colP[col0 + (2 * p + 1) * 256];
        cx[p] = (v2f){c0.x, c1.x};
        cy[p] = (v2f){c0.y, c1.y};
        cz[p] = (v2f){c0.z, c1.z};
        cw[p] = (v2f){c0.w * INV_EPS_L2E, c1.w * INV_EPS_L2E};
    }
    v2f mx[4];
#pragma unroll
    for (int p = 0; p < 4; p++) mx[p] = -3.4e38f;
#pragma unroll 4
    for (int rr = 0; rr < CHUNK; rr++) {
        float4 rp = srow[rr];
        v2f rx = rp.x, ry = rp.y, rz = rp.z, rw = rp.w;
#pragma unroll
        for (int p = 0; p < 4; p++) {
            v2f e = rw;
            e = __builtin_elementwise_fma(rx, cx[p], e);
            e = __builtin_elementwise_fma(ry, cy[p], e);
            e = __builtin_elementwise_fma(rz, cz[p], e);
            mx[p] = __builtin_elementwise_max(mx[p], e);
        }
    }
    v2f sa[4];
#pragma unroll
    for (int p = 0; p < 4; p++) sa[p] = 0.0f;
#pragma unroll 4
    for (int rr = 0; rr < CHUNK; rr++) {
        float4 rp = srow[rr];
        v2f rx = rp.x, ry = rp.y, rz = rp.z, rw = rp.w;
#pragma unroll
        for (int p = 0; p < 4; p++) {
            v2f e = rw - mx[p];
            e = __builtin_elementwise_fma(rx, cx[p], e);
            e = __builtin_elementwise_fma(ry, cy[p], e);
            e = __builtin_elementwise_fma(rz, cz[p], e);
            v2f ex;
            ex.x = __builtin_amdgcn_exp2f(e.x);
            ex.y = __builtin_amdgcn_exp2f(e.y);
            sa[p] += ex;
        }
    }
    float2* om = Pout + q * QSTRIDE + chunk * NPTS;
#pragma unroll
    for (int p = 0; p < 4; p++) {
        v2f mstore = mx[p] - cw[p];
        om[col0 + (2 * p) * 256]     = make_float2(mstore.x, sa[p].x);
        om[col0 + (2 * p + 1) * 256] = make_float2(mstore.y, sa[p].y);
    }
}

// ---------------- sinkhorn value: f.mean() + g.mean() per problem ----------------
// grid (256, 6): blockIdx.x>>7 selects f/g partials, &127 selects the 32-row chunk.
__global__ __launch_bounds__(256) void egf_sink_val6(const float2* __restrict__ Pf,
                                                     const float2* __restrict__ Pg,
                                                     float* __restrict__ acc) {
    int q = blockIdx.y;
    int side = blockIdx.x >> 7;
    int chunk = blockIdx.x & 127;
    const float2* P = side ? Pg : Pf;
    __shared__ float sm[256], ss[256];
    int tid = threadIdx.x;
    int r_local = tid & 31, h = tid >> 5;
    int row = chunk * CHUNK + r_local;
    float v = stageCombine(P, q * QSTRIDE, row, h, sm, ss, tid);
    float tot = blockSum(v, tid);
    if (tid == 0) atomicAdd(&acc[A_SINK + q], tot * (1.0f / 4096.0f));
}

// ---------------- final scalar assembly ----------------
__global__ void egf_finalize(const float* __restrict__ acc, float* __restrict__ out) {
    if (threadIdx.x != 0 || blockIdx.x != 0) return;
    const float AREA = 246.0f * 246.0f;
    float ssim_m = 1.0f - (acc[A_SSIMA] + acc[A_SSIMA + 1]) / (2.0f * AREA);
    float ssim_p = 1.0f - (acc[A_SSIMB] + acc[A_SSIMB + 1]) / (2.0f * 3.0f * AREA);
    float g_cons = acc[A_CH1] / (2.0f * 65536.0f) + acc[A_CH2] / (2.0f * 16384.0f);
    float aux = acc[A_AUX] / (2.0f * 65536.0f);
    float inc0 = (acc[A_CNT]     >= 31.5f) ? 1.0f : 0.0f;
    float inc1 = (acc[A_CNT + 1] >= 31.5f) ? 1.0f : 0.0f;
    const float* v = acc + A_SINK;
    float Lt = (inc0 * (v[0] - 0.5f * v[1] - 0.5f * v[2]) +
                inc1 * (v[3] - 0.5f * v[4] - 0.5f * v[5])) * 0.5f;
    float Lo = (inc0 * acc[A_LOUT] + inc1 * acc[A_LOUT + 1]) / (3.0f * 65536.0f) * 0.5f;
    float Ls = (inc0 * (1.0f - acc[A_SSIMC] / (3.0f * AREA)) +
                inc1 * (1.0f - acc[A_SSIMC + 1] / (3.0f * AREA))) * 0.5f;
    float Li = 2.5f * acc[A_INT] / (2.0f * 3.0f * 65536.0f);
    float Lsm = acc[A_SMOOTH] / (2.0f * 3.0f * 65536.0f);
    float total = 0.8f * Lt + 0.3f * Lo + 0.5f * Ls + Li + 0.2f * Lsm;
    out[0] = total; out[1] = ssim_m; out[2] = ssim_p; out[3] = g_cons; out[4] = aux;
}

// ---------------- host launch ----------------
extern "C" void kernel_launch(void* const* d_in, const int* in_sizes, int n_in,
                              void* d_out, int out_size, void* d_ws, size_t ws_size,
                              hipStream_t stream) {
    const float* y    = (const float*)d_in[0];
    const float* mri  = (const float*)d_in[1];
    const float* pet  = (const float*)d_in[2];
    const float* mask = (const float*)d_in[3];
    const float* ehat = (const float*)d_in[4];
    const int*   idx  = (const int*)d_in[5];
    float* out = (float*)d_out;
    float* ws  = (float*)d_ws;

    float* acc   = ws;                    // 64 floats
    float4* pts  = (float4*)(ws + 64);    // 4*4096 float4 = 65536 floats
    float* base  = ws + 64 + 65536;

    // sinkhorn partials: 2 float2-planes of 6*128*4096 elements each (25 MB apiece)
    float2* Pf = (float2*)base;
    float2* Pg = Pf + QSTRIDE * 6;
    float* ibase = base + 4 * QSTRIDE * 6;   // 2 planes * 2 floats/elem

    // image scratch
    float* ygray    = ibase;              // 131072
    float* py       = ygray + 131072;     // 32768
    float* pmri     = py + 32768;         // 32768
    float* mag_yg   = pmri + 32768;       // 131072
    float* mag_mri  = mag_yg + 131072;    // 131072
    float* mag_py   = mag_mri + 131072;   // 32768
    float* mag_pmri = mag_py + 32768;     // 32768
    float* tmp      = mag_pmri + 32768;   // 393216

    hipMemsetAsync(acc, 0, 64 * sizeof(float), stream);

    unsigned* mx = (unsigned*)(acc + A_MAX);

    egf_prep<<<dim3(256, 2), 256, 0, stream>>>(y, pet, mask, ygray, acc);
    egf_pool<<<dim3(64, 2), 256, 0, stream>>>(y, mri, py, pmri);
    egf_sobel<<<dim3(256, 2), 256, 0, stream>>>(ygray, mag_yg, mx + 0, 256, 8);
    egf_sobel<<<dim3(256, 2), 256, 0, stream>>>(mri, mag_mri, mx + 2, 256, 8);
    egf_sobel<<<dim3(64, 2), 256, 0, stream>>>(py, mag_py, mx + 4, 128, 7);
    egf_sobel<<<dim3(64, 2), 256, 0, stream>>>(pmri, mag_pmri, mx + 6, 128, 7);
    egf_charb<<<dim3(256, 2), 256, 0, stream>>>(mag_yg, mag_mri, mx + 0, mx + 2, ehat,
                                                acc + A_CH1, acc + A_AUX, 65536);
    egf_charb<<<dim3(64, 2), 256, 0, stream>>>(mag_py, mag_pmri, mx + 4, mx + 6, nullptr,
                                               acc + A_CH2, nullptr, 16384);
    egf_ssim<<<dim3(16, 16, 2), dim3(16, 16), 0, stream>>>(ygray, 65536, 0, mri, 65536, 0,
                                                           nullptr, 1, acc + A_SSIMA);
    egf_ssim<<<dim3(16, 16, 6), dim3(16, 16), 0, stream>>>(y, 196608, 65536, pet, 196608, 65536,
                                                           nullptr, 3, acc + A_SSIMB);
    egf_ssim<<<dim3(16, 16, 6), dim3(16, 16), 0, stream>>>(y, 196608, 65536, mri, 65536, 0,
                                                           mask, 3, acc + A_SSIMC);
    egf_smoothV<<<1536, 256, 0, stream>>>(y, tmp);
    egf_smoothH<<<1536, 256, 0, stream>>>(tmp, y, acc + A_SMOOTH);
    egf_gather<<<32, 256, 0, stream>>>(y, pet, mask, idx, pts);

    dim3 sgrid(NCB, NCH, 6);   // 2 x 128 x 6 = 1536 blocks
    for (int it = 0; it < 11; ++it) {
        egf_sink_half6<<<sgrid, 256, 0, stream>>>(pts, Pf, Pg, 0, it == 0 ? 1 : 0);
        egf_sink_half6<<<sgrid, 256, 0, stream>>>(pts, Pg, Pf, 1, 0);
    }
    egf_sink_val6<<<dim3(256, 6), 256, 0, stream>>>(Pf, Pg, acc);
    egf_finalize<<<1, 64, 0, stream>>>(acc, out);
}

// Round 9
// 885.633 us; speedup vs baseline: 2.3323x; 1.0879x over previous
//
#include <hip/hip_runtime.h>
#include <math.h>

// ---------------- constants ----------------
#define INV_EPS_L2E 577.0780163555854f   // (1/eps) * log2(e) = 1/(eps*ln2)
#define EPS_LOGN 0.02079441542f          // eps * ln(4096) = -eps*loga
#define EPS_LN2 0.00173286795f           // eps * ln(2)

#define NPTS 4096
#define CHUNK 64
#define NCH 64            // 4096/64
#define CPT 8             // columns per thread (4 packed pairs)
#define COLS_PER_BLK 2048 // 256*CPT
#define NCB 2             // 4096/2048
#define QSTRIDE (NCH * NPTS)  // float2 elements per problem in partial arrays

typedef float v2f __attribute__((ext_vector_type(2)));

// true packed-fp32 ops (LLVM won't auto-form these from vector IR)
__device__ __forceinline__ v2f pk_fma(v2f a, v2f b, v2f c) {
    v2f d;
    asm("v_pk_fma_f32 %0, %1, %2, %3" : "=v"(d) : "v"(a), "v"(b), "v"(c));
    return d;
}
__device__ __forceinline__ v2f pk_add(v2f a, v2f b) {
    v2f d;
    asm("v_pk_add_f32 %0, %1, %2" : "=v"(d) : "v"(a), "v"(b));
    return d;
}

// accumulator slots (floats) at start of workspace
constexpr int A_SSIMA  = 0;   // [B]
constexpr int A_SSIMB  = 2;   // [B]
constexpr int A_SSIMC  = 4;   // [B]
constexpr int A_CH1    = 6;
constexpr int A_CH2    = 7;
constexpr int A_AUX    = 8;
constexpr int A_INT    = 9;
constexpr int A_LOUT   = 10;  // [B]
constexpr int A_CNT    = 12;  // [B]
constexpr int A_SMOOTH = 14;
constexpr int A_SINK   = 16;  // [6]
constexpr int A_MAX    = 32;  // 8 uint slots (4 fields x B), float-bits

// ---------------- block reduction helpers (blockDim == 256) ----------------
__device__ __forceinline__ float blockSum(float v, int tid) {
#pragma unroll
    for (int o = 32; o; o >>= 1) v += __shfl_down(v, o, 64);
    __shared__ float sh[4];
    __syncthreads();
    if ((tid & 63) == 0) sh[tid >> 6] = v;
    __syncthreads();
    return sh[0] + sh[1] + sh[2] + sh[3];
}

__device__ __forceinline__ float blockMax(float v, int tid) {
#pragma unroll
    for (int o = 32; o; o >>= 1) v = fmaxf(v, __shfl_down(v, o, 64));
    __shared__ float sh[4];
    __syncthreads();
    if ((tid & 63) == 0) sh[tid >> 6] = v;
    __syncthreads();
    return fmaxf(fmaxf(sh[0], sh[1]), fmaxf(sh[2], sh[3]));
}

// ---------------- prep: y_gray, intensity, L_out, mask count ----------------
__global__ __launch_bounds__(256) void egf_prep(const float* __restrict__ y,
                                                const float* __restrict__ pet,
                                                const float* __restrict__ mask,
                                                float* __restrict__ ygray,
                                                float* __restrict__ acc) {
    int b = blockIdx.y;
    int p = blockIdx.x * 256 + threadIdx.x;      // exactly 65536
    float m  = mask[b * 65536 + p];
    float y0 = y[(b * 3 + 0) * 65536 + p];
    float y1 = y[(b * 3 + 1) * 65536 + p];
    float y2 = y[(b * 3 + 2) * 65536 + p];
    float q0 = pet[(b * 3 + 0) * 65536 + p];
    float q1 = pet[(b * 3 + 1) * 65536 + p];
    float q2 = pet[(b * 3 + 2) * 65536 + p];
    ygray[b * 65536 + p] = (y0 + y1 + y2) * (1.0f / 3.0f);
    float d0 = m * y0 - m * q0, d1 = m * y1 - m * q1, d2 = m * y2 - m * q2;
    float inten = d0 * d0 + d1 * d1 + d2 * d2;
    float im = 1.0f - m;
    float o0 = y0 * im, o1 = y1 * im, o2 = y2 * im;
    float lout = o0 * o0 + o1 * o1 + o2 * o2;
    float cnt = (m > 0.1f) ? 1.0f : 0.0f;
    float t;
    t = blockSum(inten, threadIdx.x); if (threadIdx.x == 0) atomicAdd(&acc[A_INT], t);
    t = blockSum(lout,  threadIdx.x); if (threadIdx.x == 0) atomicAdd(&acc[A_LOUT + b], t);
    t = blockSum(cnt,   threadIdx.x); if (threadIdx.x == 0) atomicAdd(&acc[A_CNT + b], t);
}

// ---------------- avgpool2 (y channel-mean, mri) ----------------
__global__ __launch_bounds__(256) void egf_pool(const float* __restrict__ y,
                                                const float* __restrict__ mri,
                                                float* __restrict__ py,
                                                float* __restrict__ pmri) {
    int b = blockIdx.y;
    int po = blockIdx.x * 256 + threadIdx.x;     // exactly 16384
    int i = po >> 7, j = po & 127;
    int p0 = (i * 2) * 256 + j * 2;
    float s = 0.0f;
#pragma unroll
    for (int c = 0; c < 3; c++) {
        const float* ip = y + (b * 3 + c) * 65536;
        s += ip[p0] + ip[p0 + 1] + ip[p0 + 256] + ip[p0 + 257];
    }
    py[b * 16384 + po] = s * (1.0f / 12.0f);
    const float* mp = mri + b * 65536;
    pmri[b * 16384 + po] = (mp[p0] + mp[p0 + 1] + mp[p0 + 256] + mp[p0 + 257]) * 0.25f;
}

// ---------------- sobel magnitude + per-sample max ----------------
__global__ __launch_bounds__(256) void egf_sobel(const float* __restrict__ in,
                                                 float* __restrict__ mag,
                                                 unsigned* __restrict__ mx,
                                                 int H, int logH) {
    int b = blockIdx.y;
    int p = blockIdx.x * 256 + threadIdx.x;
    int HH = H * H;
    const float* ip = in + b * HH;
    int i = p >> logH, j = p & (H - 1);
    auto at = [&](int ii, int jj) -> float {
        return (ii >= 0 && ii < H && jj >= 0 && jj < H) ? ip[(ii << logH) + jj] : 0.0f;
    };
    float a00 = at(i - 1, j - 1), a01 = at(i - 1, j), a02 = at(i - 1, j + 1);
    float a10 = at(i, j - 1),                         a12 = at(i, j + 1);
    float a20 = at(i + 1, j - 1), a21 = at(i + 1, j), a22 = at(i + 1, j + 1);
    float gx = a00 - a02 + 2.0f * a10 - 2.0f * a12 + a20 - a22;
    float gy = a00 + 2.0f * a01 + a02 - a20 - 2.0f * a21 - a22;
    float m = sqrtf(gx * gx + gy * gy + 1e-6f);
    mag[b * HH + p] = m;
    float bm = blockMax(m, threadIdx.x);
    if (threadIdx.x == 0) atomicMax(mx + b, __float_as_uint(bm));
}

// ---------------- charbonnier(+aux) over a normalized sobel pair ----------------
__global__ __launch_bounds__(256) void egf_charb(const float* __restrict__ magA,
                                                 const float* __restrict__ magB,
                                                 const unsigned* __restrict__ mxA,
                                                 const unsigned* __restrict__ mxB,
                                                 const float* __restrict__ ehat,
                                                 float* __restrict__ accC,
                                                 float* __restrict__ accAux,
                                                 int HH) {
    int b = blockIdx.y;
    int p = blockIdx.x * 256 + threadIdx.x;
    float c = 0.0f, au = 0.0f;
    float da = fmaxf(__uint_as_float(mxA[b]), 1e-6f);
    float db = fmaxf(__uint_as_float(mxB[b]), 1e-6f);
    if (p < HH) {
        float sa = magA[b * HH + p] / da;
        float sb = magB[b * HH + p] / db;
        float d = sa - sb;
        c = sqrtf(d * d + 1e-6f);
        if (ehat) au = fabsf(ehat[b * HH + p] - sb);
    }
    float tc = blockSum(c, threadIdx.x);
    if (threadIdx.x == 0) atomicAdd(accC, tc);
    if (ehat) {
        float ta = blockSum(au, threadIdx.x);
        if (threadIdx.x == 0) atomicAdd(accAux, ta);
    }
}

// ---------------- SSIM (11x11 gaussian, VALID -> 246x246), per-b sums ----------------
__global__ __launch_bounds__(256) void egf_ssim(const float* __restrict__ X, int xBS, int xCS,
                                                const float* __restrict__ Y, int yBS, int yCS,
                                                const float* __restrict__ M,
                                                int C_, float* __restrict__ accB) {
    int bc = blockIdx.z; int b = bc / C_; int c = bc - b * C_;
    const float* xp = X + b * xBS + c * xCS;
    const float* yp = Y + b * yBS + c * yCS;
    const float* mp = M ? (M + b * 65536) : nullptr;
    __shared__ float sx[26][27];
    __shared__ float sy[26][27];
    int ti = blockIdx.x * 16, tj = blockIdx.y * 16;
    int tid = threadIdx.y * 16 + threadIdx.x;
    for (int t = tid; t < 26 * 26; t += 256) {
        int li = t / 26, lj = t - li * 26;
        int gi = ti + li, gj = tj + lj;
        float a = 0.0f, bb = 0.0f;
        if (gi < 256 && gj < 256) {
            int p = (gi << 8) + gj;
            float m = mp ? mp[p] : 1.0f;
            a = xp[p] * m; bb = yp[p] * m;
        }
        sx[li][lj] = a; sy[li][lj] = bb;
    }
    __syncthreads();
    float w[11];
    {
        float s = 0.0f;
#pragma unroll
        for (int i = 0; i < 11; i++) { float d = (float)(i - 5); w[i] = expf(-d * d * (1.0f / 4.5f)); s += w[i]; }
        float inv = 1.0f / s;
#pragma unroll
        for (int i = 0; i < 11; i++) w[i] *= inv;
    }
    int oi = ti + threadIdx.y, oj = tj + threadIdx.x;
    float val = 0.0f;
    if (oi < 246 && oj < 246) {
        float mu1 = 0, mu2 = 0, xx = 0, yy = 0, xy = 0;
        for (int di = 0; di < 11; di++) {
            float wi = w[di];
#pragma unroll
            for (int dj = 0; dj < 11; dj++) {
                float ww = wi * w[dj];
                float a  = sx[threadIdx.y + di][threadIdx.x + dj];
                float bb = sy[threadIdx.y + di][threadIdx.x + dj];
                mu1 += ww * a; mu2 += ww * bb;
                xx += ww * a * a; yy += ww * bb * bb; xy += ww * a * bb;
            }
        }
        float s11 = xx - mu1 * mu1, s22 = yy - mu2 * mu2, s12 = xy - mu1 * mu2;
        const float C1 = 1e-4f, C2 = 9e-4f;
        val = ((2.0f * mu1 * mu2 + C1) * (2.0f * s12 + C2)) /
              ((mu1 * mu1 + mu2 * mu2 + C1) * (s11 + s22 + C2));
    }
    float tot = blockSum(val, tid);
    if (tid == 0) atomicAdd(&accB[b], tot);
}

// ---------------- gaussian smooth (9-tap sigma=1, symmetric pad), two passes ----------------
__device__ __forceinline__ int refl256(int i) { return i < 0 ? -1 - i : (i > 255 ? 511 - i : i); }

__device__ __forceinline__ void gauss9(float* w) {
    float s = 0.0f;
#pragma unroll
    for (int t = 0; t < 9; t++) { float d = (float)(t - 4); w[t] = expf(-0.5f * d * d); s += w[t]; }
    float inv = 1.0f / s;
#pragma unroll
    for (int t = 0; t < 9; t++) w[t] *= inv;
}

__global__ __launch_bounds__(256) void egf_smoothV(const float* __restrict__ y, float* __restrict__ tmp) {
    int g = blockIdx.x * 256 + threadIdx.x;      // < 393216
    int bc = g >> 16; int p = g & 65535; int i = p >> 8, j = p & 255;
    float w[9]; gauss9(w);
    const float* ip = y + bc * 65536;
    float s = 0.0f;
#pragma unroll
    for (int t = 0; t < 9; t++) s += w[t] * ip[(refl256(i + t - 4) << 8) + j];
    tmp[g] = s;
}

__global__ __launch_bounds__(256) void egf_smoothH(const float* __restrict__ tmp,
                                                   const float* __restrict__ y,
                                                   float* __restrict__ acc) {
    int g = blockIdx.x * 256 + threadIdx.x;
    int bc = g >> 16; int p = g & 65535; int i = p >> 8, j = p & 255;
    float w[9]; gauss9(w);
    const float* tp = tmp + bc * 65536;
    float s = 0.0f;
#pragma unroll
    for (int t = 0; t < 9; t++) s += w[t] * tp[(i << 8) + refl256(j + t - 4)];
    float d = s - y[g];
    float tt = blockSum(d * d, threadIdx.x);
    if (threadIdx.x == 0) atomicAdd(acc, tt);
}

// ---------------- gather masked point clouds ----------------
__global__ __launch_bounds__(256) void egf_gather(const float* __restrict__ y,
                                                  const float* __restrict__ pet,
                                                  const float* __restrict__ mask,
                                                  const int* __restrict__ idx,
                                                  float4* __restrict__ pts) {
    int t = blockIdx.x * 256 + threadIdx.x;      // < 8192
    int b = t >> 12, j = t & 4095;
    int p = idx[b * 4096 + j];
    float m = mask[b * 65536 + p];
    float a0 = y[(b * 3 + 0) * 65536 + p] * m;
    float a1 = y[(b * 3 + 1) * 65536 + p] * m;
    float a2 = y[(b * 3 + 2) * 65536 + p] * m;
    pts[(b * 2 + 0) * 4096 + j] = make_float4(a0, a1, a2, 0.5f * (a0 * a0 + a1 * a1 + a2 * a2));
    float c0 = pet[(b * 3 + 0) * 65536 + p] * m;
    float c1 = pet[(b * 3 + 1) * 65536 + p] * m;
    float c2 = pet[(b * 3 + 2) * 65536 + p] * m;
    pts[(b * 2 + 1) * 4096 + j] = make_float4(c0, c1, c2, 0.5f * (c0 * c0 + c1 * c1 + c2 * c2));
}

// ---------------- fused combine (staging) helper, NCH=64, float2 partials ----
// 4 threads per row (h = tid>>6), 16 chunk-partials each; coalesced 8B loads.
// Returns potential v for tid<64.
__device__ __forceinline__ float stageCombine(const float2* __restrict__ Pin,
                                              int qbase, int row, int h, int r_local,
                                              float* sm, float* ss, int tid) {
    const float2* p = Pin + qbase + (h * 16) * NPTS + row;
    float2 t[16];
#pragma unroll
    for (int k = 0; k < 16; k++) t[k] = p[k * NPTS];
    float m16 = -3.4e38f;
#pragma unroll
    for (int k = 0; k < 16; k++) m16 = fmaxf(m16, t[k].x);
    float s16 = 0.0f;
#pragma unroll
    for (int k = 0; k < 16; k++) s16 += t[k].y * __builtin_amdgcn_exp2f(t[k].x - m16);
    sm[h * 64 + r_local] = m16;
    ss[h * 64 + r_local] = s16;
    __syncthreads();
    float v = 0.0f;
    if (tid < 64) {
        float m0 = sm[tid], m1 = sm[64 + tid], m2 = sm[128 + tid], m3 = sm[192 + tid];
        float M = fmaxf(fmaxf(m0, m1), fmaxf(m2, m3));
        float S = ss[tid]       * __builtin_amdgcn_exp2f(m0 - M) +
                  ss[64 + tid]  * __builtin_amdgcn_exp2f(m1 - M) +
                  ss[128 + tid] * __builtin_amdgcn_exp2f(m2 - M) +
                  ss[192 + tid] * __builtin_amdgcn_exp2f(m3 - M);
        v = EPS_LOGN - EPS_LN2 * (M + log2f(S));
    }
    return v;
}

// ---------------- sinkhorn half: true-packed fp32, CHUNK=64, CPT=8 ----------
// log2-domain. Rows staged as pre-duplicated v2f pairs in LDS.
// Stored partial m = max_r(a_r + dot) - b_c; b_c cancels in pass 2.
__global__ __launch_bounds__(256) void egf_sink_half7(const float4* __restrict__ pts,
                                                      const float2* __restrict__ Pin,
                                                      float2* __restrict__ Pout,
                                                      int dir, int init) {
    int q = blockIdx.z; int b = q / 3, t = q - b * 3;
    int xsel = (t == 2) ? 1 : 0;
    int ysel = (t == 1) ? 0 : 1;
    const float4* rowP = pts + (b * 2 + (dir ? ysel : xsel)) * NPTS;
    const float4* colP = pts + (b * 2 + (dir ? xsel : ysel)) * NPTS;

    __shared__ v2f srowd[CHUNK][4];    // {x,x},{y,y},{z,z},{w,w} per row (K2-scaled)
    __shared__ float sm[256], ss[256];
    int tid = threadIdx.x;
    int chunk = blockIdx.y;
    int r_local = tid & 63, h = tid >> 6;
    int row = chunk * CHUNK + r_local;

    float v = 0.0f;
    if (!init)
        v = stageCombine(Pin, q * QSTRIDE, row, h, r_local, sm, ss, tid);
    if (tid < 64) {
        float4 pp = rowP[row];
        float sx = pp.x * INV_EPS_L2E, sy = pp.y * INV_EPS_L2E;
        float sz = pp.z * INV_EPS_L2E, sw = (v - pp.w) * INV_EPS_L2E;
        srowd[tid][0] = (v2f){sx, sx};
        srowd[tid][1] = (v2f){sy, sy};
        srowd[tid][2] = (v2f){sz, sz};
        srowd[tid][3] = (v2f){sw, sw};
    }
    __syncthreads();

    int col0 = blockIdx.x * COLS_PER_BLK + tid;
    v2f cx[4], cy[4], cz[4], cw[4];
#pragma unroll
    for (int p = 0; p < 4; p++) {
        float4 c0 = colP[col0 + (2 * p) * 256];
        float4 c1 = colP[col0 + (2 * p + 1) * 256];
        cx[p] = (v2f){c0.x, c1.x};
        cy[p] = (v2f){c0.y, c1.y};
        cz[p] = (v2f){c0.z, c1.z};
        cw[p] = (v2f){c0.w * INV_EPS_L2E, c1.w * INV_EPS_L2E};
    }
    v2f mx[4];
#pragma unroll
    for (int p = 0; p < 4; p++) mx[p] = (v2f){-3.4e38f, -3.4e38f};
#pragma unroll 4
    for (int rr = 0; rr < CHUNK; rr++) {
        v2f rx = srowd[rr][0], ry = srowd[rr][1], rz = srowd[rr][2], rw = srowd[rr][3];
#pragma unroll
        for (int p = 0; p < 4; p++) {
            v2f e = pk_fma(rz, cz[p], rw);
            e = pk_fma(ry, cy[p], e);
            e = pk_fma(rx, cx[p], e);
            mx[p].x = fmaxf(mx[p].x, e.x);
            mx[p].y = fmaxf(mx[p].y, e.y);
        }
    }
    v2f mneg[4];
    float sax[4], say[4];
#pragma unroll
    for (int p = 0; p < 4; p++) { mneg[p] = -mx[p]; sax[p] = 0.0f; say[p] = 0.0f; }
#pragma unroll 4
    for (int rr = 0; rr < CHUNK; rr++) {
        v2f rx = srowd[rr][0], ry = srowd[rr][1], rz = srowd[rr][2], rw = srowd[rr][3];
#pragma unroll
        for (int p = 0; p < 4; p++) {
            v2f e = pk_fma(rz, cz[p], mneg[p]);
            e = pk_fma(ry, cy[p], e);
            e = pk_fma(rx, cx[p], e);
            e = pk_add(e, rw);
            sax[p] += __builtin_amdgcn_exp2f(e.x);
            say[p] += __builtin_amdgcn_exp2f(e.y);
        }
    }
    float2* om = Pout + q * QSTRIDE + chunk * NPTS;
#pragma unroll
    for (int p = 0; p < 4; p++) {
        om[col0 + (2 * p) * 256]     = make_float2(mx[p].x - cw[p].x, sax[p]);
        om[col0 + (2 * p + 1) * 256] = make_float2(mx[p].y - cw[p].y, say[p]);
    }
}

// ---------------- sinkhorn value: f.mean() + g.mean() per problem ----------------
// grid (128, 6): blockIdx.x>>6 selects f/g partials, &63 selects the 64-row chunk.
__global__ __launch_bounds__(256) void egf_sink_val7(const float2* __restrict__ Pf,
                                                     const float2* __restrict__ Pg,
                                                     float* __restrict__ acc) {
    int q = blockIdx.y;
    int side = blockIdx.x >> 6;
    int chunk = blockIdx.x & 63;
    const float2* P = side ? Pg : Pf;
    __shared__ float sm[256], ss[256];
    int tid = threadIdx.x;
    int r_local = tid & 63, h = tid >> 6;
    int row = chunk * CHUNK + r_local;
    float v = stageCombine(P, q * QSTRIDE, row, h, r_local, sm, ss, tid);
    float tot = blockSum(v, tid);
    if (tid == 0) atomicAdd(&acc[A_SINK + q], tot * (1.0f / 4096.0f));
}

// ---------------- final scalar assembly ----------------
__global__ void egf_finalize(const float* __restrict__ acc, float* __restrict__ out) {
    if (threadIdx.x != 0 || blockIdx.x != 0) return;
    const float AREA = 246.0f * 246.0f;
    float ssim_m = 1.0f - (acc[A_SSIMA] + acc[A_SSIMA + 1]) / (2.0f * AREA);
    float ssim_p = 1.0f - (acc[A_SSIMB] + acc[A_SSIMB + 1]) / (2.0f * 3.0f * AREA);
    float g_cons = acc[A_CH1] / (2.0f * 65536.0f) + acc[A_CH2] / (2.0f * 16384.0f);
    float aux = acc[A_AUX] / (2.0f * 65536.0f);
    float inc0 = (acc[A_CNT]     >= 31.5f) ? 1.0f : 0.0f;
    float inc1 = (acc[A_CNT + 1] >= 31.5f) ? 1.0f : 0.0f;
    const float* v = acc + A_SINK;
    float Lt = (inc0 * (v[0] - 0.5f * v[1] - 0.5f * v[2]) +
                inc1 * (v[3] - 0.5f * v[4] - 0.5f * v[5])) * 0.5f;
    float Lo = (inc0 * acc[A_LOUT] + inc1 * acc[A_LOUT + 1]) / (3.0f * 65536.0f) * 0.5f;
    float Ls = (inc0 * (1.0f - acc[A_SSIMC] / (3.0f * AREA)) +
                inc1 * (1.0f - acc[A_SSIMC + 1] / (3.0f * AREA))) * 0.5f;
    float Li = 2.5f * acc[A_INT] / (2.0f * 3.0f * 65536.0f);
    float Lsm = acc[A_SMOOTH] / (2.0f * 3.0f * 65536.0f);
    float total = 0.8f * Lt + 0.3f * Lo + 0.5f * Ls + Li + 0.2f * Lsm;
    out[0] = total; out[1] = ssim_m; out[2] = ssim_p; out[3] = g_cons; out[4] = aux;
}

// ---------------- host launch ----------------
extern "C" void kernel_launch(void* const* d_in, const int* in_sizes, int n_in,
                              void* d_out, int out_size, void* d_ws, size_t ws_size,
                              hipStream_t stream) {
    const float* y    = (const float*)d_in[0];
    const float* mri  = (const float*)d_in[1];
    const float* pet  = (const float*)d_in[2];
    const float* mask = (const float*)d_in[3];
    const float* ehat = (const float*)d_in[4];
    const int*   idx  = (const int*)d_in[5];
    float* out = (float*)d_out;
    float* ws  = (float*)d_ws;

    float* acc   = ws;                    // 64 floats
    float4* pts  = (float4*)(ws + 64);    // 4*4096 float4 = 65536 floats
    float* base  = ws + 64 + 65536;

    // sinkhorn partials: 2 float2-planes of 6*64*4096 elements (12.6 MB apiece)
    float2* Pf = (float2*)base;
    float2* Pg = Pf + QSTRIDE * 6;
    float* ibase = base + 4 * QSTRIDE * 6;   // 2 planes * 2 floats/elem

    // image scratch
    float* ygray    = ibase;              // 131072
    float* py       = ygray + 131072;     // 32768
    float* pmri     = py + 32768;         // 32768
    float* mag_yg   = pmri + 32768;       // 131072
    float* mag_mri  = mag_yg + 131072;    // 131072
    float* mag_py   = mag_mri + 131072;   // 32768
    float* mag_pmri = mag_py + 32768;     // 32768
    float* tmp      = mag_pmri + 32768;   // 393216

    hipMemsetAsync(acc, 0, 64 * sizeof(float), stream);

    unsigned* mx = (unsigned*)(acc + A_MAX);

    egf_prep<<<dim3(256, 2), 256, 0, stream>>>(y, pet, mask, ygray, acc);
    egf_pool<<<dim3(64, 2), 256, 0, stream>>>(y, mri, py, pmri);
    egf_sobel<<<dim3(256, 2), 256, 0, stream>>>(ygray, mag_yg, mx + 0, 256, 8);
    egf_sobel<<<dim3(256, 2), 256, 0, stream>>>(mri, mag_mri, mx + 2, 256, 8);
    egf_sobel<<<dim3(64, 2), 256, 0, stream>>>(py, mag_py, mx + 4, 128, 7);
    egf_sobel<<<dim3(64, 2), 256, 0, stream>>>(pmri, mag_pmri, mx + 6, 128, 7);
    egf_charb<<<dim3(256, 2), 256, 0, stream>>>(mag_yg, mag_mri, mx + 0, mx + 2, ehat,
                                                acc + A_CH1, acc + A_AUX, 65536);
    egf_charb<<<dim3(64, 2), 256, 0, stream>>>(mag_py, mag_pmri, mx + 4, mx + 6, nullptr,
                                               acc + A_CH2, nullptr, 16384);
    egf_ssim<<<dim3(16, 16, 2), dim3(16, 16), 0, stream>>>(ygray, 65536, 0, mri, 65536, 0,
                                                           nullptr, 1, acc + A_SSIMA);
    egf_ssim<<<dim3(16, 16, 6), dim3(16, 16), 0, stream>>>(y, 196608, 65536, pet, 196608, 65536,
                                                           nullptr, 3, acc + A_SSIMB);
    egf_ssim<<<dim3(16, 16, 6), dim3(16, 16), 0, stream>>>(y, 196608, 65536, mri, 65536, 0,
                                                           mask, 3, acc + A_SSIMC);
    egf_smoothV<<<1536, 256, 0, stream>>>(y, tmp);
    egf_smoothH<<<1536, 256, 0, stream>>>(tmp, y, acc + A_SMOOTH);
    egf_gather<<<32, 256, 0, stream>>>(y, pet, mask, idx, pts);

    dim3 sgrid(NCB, NCH, 6);   // 2 x 64 x 6 = 768 blocks
    for (int it = 0; it < 11; ++it) {
        egf_sink_half7<<<sgrid, 256, 0, stream>>>(pts, Pf, Pg, 0, it == 0 ? 1 : 0);
        egf_sink_half7<<<sgrid, 256, 0, stream>>>(pts, Pg, Pf, 1, 0);
    }
    egf_sink_val7<<<dim3(128, 6), 256, 0, stream>>>(Pf, Pg, acc);
    egf_finalize<<<1, 64, 0, stream>>>(acc, out);
}

// Round 10
// 842.077 us; speedup vs baseline: 2.4529x; 1.0517x over previous
//
#include <hip/hip_runtime.h>
#include <math.h>

// ---------------- constants ----------------
#define INV_EPS_L2E 577.0780163555854f   // (1/eps) * log2(e) = 1/(eps*ln2)
#define EPS_LOGN 0.02079441542f          // eps * ln(4096) = -eps*loga
#define EPS_LN2 0.00173286795f           // eps * ln(2)

#define NPTS 4096
#define CHUNK 64
#define NCH 64            // 4096/64
#define CPT 8             // columns per thread (4 packed pairs)
#define COLS_PER_BLK 2048 // 256*CPT
#define NCB 2             // 4096/2048
#define QSTRIDE (NCH * NPTS)  // float2 elements per problem in partial arrays

typedef float v2f __attribute__((ext_vector_type(2)));

// True packed-fp32 ops with VOP3P op_sel broadcasts.
// Semantics: op_sel[i] picks src-i half for LOW result lane; op_sel_hi[i] for HIGH.
// Defaults (normal packed): op_sel:[0,0,0] op_sel_hi:[1,1,1].
__device__ __forceinline__ v2f pk_fma(v2f a, v2f b, v2f c) {
    v2f d;
    asm("v_pk_fma_f32 %0, %1, %2, %3" : "=v"(d) : "v"(a), "v"(b), "v"(c));
    return d;
}
// lo(a) broadcast to both lanes; b,c normal
__device__ __forceinline__ v2f pk_fma_blo(v2f a, v2f b, v2f c) {
    v2f d;
    asm("v_pk_fma_f32 %0, %1, %2, %3 op_sel:[0,0,0] op_sel_hi:[0,1,1]"
        : "=v"(d) : "v"(a), "v"(b), "v"(c));
    return d;
}
// hi(a) broadcast; b,c normal
__device__ __forceinline__ v2f pk_fma_bhi(v2f a, v2f b, v2f c) {
    v2f d;
    asm("v_pk_fma_f32 %0, %1, %2, %3 op_sel:[1,0,0] op_sel_hi:[1,1,1]"
        : "=v"(d) : "v"(a), "v"(b), "v"(c));
    return d;
}
// lo(a) broadcast AND hi(c) broadcast; b normal   (computes a.lo*b + c.hi per lane)
__device__ __forceinline__ v2f pk_fma_blo_chi(v2f a, v2f b, v2f c) {
    v2f d;
    asm("v_pk_fma_f32 %0, %1, %2, %3 op_sel:[0,0,1] op_sel_hi:[0,1,1]"
        : "=v"(d) : "v"(a), "v"(b), "v"(c));
    return d;
}
// a + hi(b) broadcast
__device__ __forceinline__ v2f pk_add_bhi(v2f a, v2f b) {
    v2f d;
    asm("v_pk_add_f32 %0, %1, %2 op_sel:[0,1] op_sel_hi:[1,1]"
        : "=v"(d) : "v"(a), "v"(b));
    return d;
}

// accumulator slots (floats) at start of workspace
constexpr int A_SSIMA  = 0;   // [B]
constexpr int A_SSIMB  = 2;   // [B]
constexpr int A_SSIMC  = 4;   // [B]
constexpr int A_CH1    = 6;
constexpr int A_CH2    = 7;
constexpr int A_AUX    = 8;
constexpr int A_INT    = 9;
constexpr int A_LOUT   = 10;  // [B]
constexpr int A_CNT    = 12;  // [B]
constexpr int A_SMOOTH = 14;
constexpr int A_SINK   = 16;  // [6]
constexpr int A_MAX    = 32;  // 8 uint slots (4 fields x B), float-bits

// ---------------- block reduction helpers (blockDim == 256) ----------------
__device__ __forceinline__ float blockSum(float v, int tid) {
#pragma unroll
    for (int o = 32; o; o >>= 1) v += __shfl_down(v, o, 64);
    __shared__ float sh[4];
    __syncthreads();
    if ((tid & 63) == 0) sh[tid >> 6] = v;
    __syncthreads();
    return sh[0] + sh[1] + sh[2] + sh[3];
}

__device__ __forceinline__ float blockMax(float v, int tid) {
#pragma unroll
    for (int o = 32; o; o >>= 1) v = fmaxf(v, __shfl_down(v, o, 64));
    __shared__ float sh[4];
    __syncthreads();
    if ((tid & 63) == 0) sh[tid >> 6] = v;
    __syncthreads();
    return fmaxf(fmaxf(sh[0], sh[1]), fmaxf(sh[2], sh[3]));
}

// ---------------- prep: y_gray, intensity, L_out, mask count ----------------
__global__ __launch_bounds__(256) void egf_prep(const float* __restrict__ y,
                                                const float* __restrict__ pet,
                                                const float* __restrict__ mask,
                                                float* __restrict__ ygray,
                                                float* __restrict__ acc) {
    int b = blockIdx.y;
    int p = blockIdx.x * 256 + threadIdx.x;      // exactly 65536
    float m  = mask[b * 65536 + p];
    float y0 = y[(b * 3 + 0) * 65536 + p];
    float y1 = y[(b * 3 + 1) * 65536 + p];
    float y2 = y[(b * 3 + 2) * 65536 + p];
    float q0 = pet[(b * 3 + 0) * 65536 + p];
    float q1 = pet[(b * 3 + 1) * 65536 + p];
    float q2 = pet[(b * 3 + 2) * 65536 + p];
    ygray[b * 65536 + p] = (y0 + y1 + y2) * (1.0f / 3.0f);
    float d0 = m * y0 - m * q0, d1 = m * y1 - m * q1, d2 = m * y2 - m * q2;
    float inten = d0 * d0 + d1 * d1 + d2 * d2;
    float im = 1.0f - m;
    float o0 = y0 * im, o1 = y1 * im, o2 = y2 * im;
    float lout = o0 * o0 + o1 * o1 + o2 * o2;
    float cnt = (m > 0.1f) ? 1.0f : 0.0f;
    float t;
    t = blockSum(inten, threadIdx.x); if (threadIdx.x == 0) atomicAdd(&acc[A_INT], t);
    t = blockSum(lout,  threadIdx.x); if (threadIdx.x == 0) atomicAdd(&acc[A_LOUT + b], t);
    t = blockSum(cnt,   threadIdx.x); if (threadIdx.x == 0) atomicAdd(&acc[A_CNT + b], t);
}

// ---------------- avgpool2 (y channel-mean, mri) ----------------
__global__ __launch_bounds__(256) void egf_pool(const float* __restrict__ y,
                                                const float* __restrict__ mri,
                                                float* __restrict__ py,
                                                float* __restrict__ pmri) {
    int b = blockIdx.y;
    int po = blockIdx.x * 256 + threadIdx.x;     // exactly 16384
    int i = po >> 7, j = po & 127;
    int p0 = (i * 2) * 256 + j * 2;
    float s = 0.0f;
#pragma unroll
    for (int c = 0; c < 3; c++) {
        const float* ip = y + (b * 3 + c) * 65536;
        s += ip[p0] + ip[p0 + 1] + ip[p0 + 256] + ip[p0 + 257];
    }
    py[b * 16384 + po] = s * (1.0f / 12.0f);
    const float* mp = mri + b * 65536;
    pmri[b * 16384 + po] = (mp[p0] + mp[p0 + 1] + mp[p0 + 256] + mp[p0 + 257]) * 0.25f;
}

// ---------------- sobel magnitude + per-sample max ----------------
__global__ __launch_bounds__(256) void egf_sobel(const float* __restrict__ in,
                                                 float* __restrict__ mag,
                                                 unsigned* __restrict__ mx,
                                                 int H, int logH) {
    int b = blockIdx.y;
    int p = blockIdx.x * 256 + threadIdx.x;
    int HH = H * H;
    const float* ip = in + b * HH;
    int i = p >> logH, j = p & (H - 1);
    auto at = [&](int ii, int jj) -> float {
        return (ii >= 0 && ii < H && jj >= 0 && jj < H) ? ip[(ii << logH) + jj] : 0.0f;
    };
    float a00 = at(i - 1, j - 1), a01 = at(i - 1, j), a02 = at(i - 1, j + 1);
    float a10 = at(i, j - 1),                         a12 = at(i, j + 1);
    float a20 = at(i + 1, j - 1), a21 = at(i + 1, j), a22 = at(i + 1, j + 1);
    float gx = a00 - a02 + 2.0f * a10 - 2.0f * a12 + a20 - a22;
    float gy = a00 + 2.0f * a01 + a02 - a20 - 2.0f * a21 - a22;
    float m = sqrtf(gx * gx + gy * gy + 1e-6f);
    mag[b * HH + p] = m;
    float bm = blockMax(m, threadIdx.x);
    if (threadIdx.x == 0) atomicMax(mx + b, __float_as_uint(bm));
}

// ---------------- charbonnier(+aux) over a normalized sobel pair ----------------
__global__ __launch_bounds__(256) void egf_charb(const float* __restrict__ magA,
                                                 const float* __restrict__ magB,
                                                 const unsigned* __restrict__ mxA,
                                                 const unsigned* __restrict__ mxB,
                                                 const float* __restrict__ ehat,
                                                 float* __restrict__ accC,
                                                 float* __restrict__ accAux,
                                                 int HH) {
    int b = blockIdx.y;
    int p = blockIdx.x * 256 + threadIdx.x;
    float c = 0.0f, au = 0.0f;
    float da = fmaxf(__uint_as_float(mxA[b]), 1e-6f);
    float db = fmaxf(__uint_as_float(mxB[b]), 1e-6f);
    if (p < HH) {
        float sa = magA[b * HH + p] / da;
        float sb = magB[b * HH + p] / db;
        float d = sa - sb;
        c = sqrtf(d * d + 1e-6f);
        if (ehat) au = fabsf(ehat[b * HH + p] - sb);
    }
    float tc = blockSum(c, threadIdx.x);
    if (threadIdx.x == 0) atomicAdd(accC, tc);
    if (ehat) {
        float ta = blockSum(au, threadIdx.x);
        if (threadIdx.x == 0) atomicAdd(accAux, ta);
    }
}

// ---------------- SSIM (11x11 gaussian, VALID -> 246x246), per-b sums ----------------
__global__ __launch_bounds__(256) void egf_ssim(const float* __restrict__ X, int xBS, int xCS,
                                                const float* __restrict__ Y, int yBS, int yCS,
                                                const float* __restrict__ M,
                                                int C_, float* __restrict__ accB) {
    int bc = blockIdx.z; int b = bc / C_; int c = bc - b * C_;
    const float* xp = X + b * xBS + c * xCS;
    const float* yp = Y + b * yBS + c * yCS;
    const float* mp = M ? (M + b * 65536) : nullptr;
    __shared__ float sx[26][27];
    __shared__ float sy[26][27];
    int ti = blockIdx.x * 16, tj = blockIdx.y * 16;
    int tid = threadIdx.y * 16 + threadIdx.x;
    for (int t = tid; t < 26 * 26; t += 256) {
        int li = t / 26, lj = t - li * 26;
        int gi = ti + li, gj = tj + lj;
        float a = 0.0f, bb = 0.0f;
        if (gi < 256 && gj < 256) {
            int p = (gi << 8) + gj;
            float m = mp ? mp[p] : 1.0f;
            a = xp[p] * m; bb = yp[p] * m;
        }
        sx[li][lj] = a; sy[li][lj] = bb;
    }
    __syncthreads();
    float w[11];
    {
        float s = 0.0f;
#pragma unroll
        for (int i = 0; i < 11; i++) { float d = (float)(i - 5); w[i] = expf(-d * d * (1.0f / 4.5f)); s += w[i]; }
        float inv = 1.0f / s;
#pragma unroll
        for (int i = 0; i < 11; i++) w[i] *= inv;
    }
    int oi = ti + threadIdx.y, oj = tj + threadIdx.x;
    float val = 0.0f;
    if (oi < 246 && oj < 246) {
        float mu1 = 0, mu2 = 0, xx = 0, yy = 0, xy = 0;
        for (int di = 0; di < 11; di++) {
            float wi = w[di];
#pragma unroll
            for (int dj = 0; dj < 11; dj++) {
                float ww = wi * w[dj];
                float a  = sx[threadIdx.y + di][threadIdx.x + dj];
                float bb = sy[threadIdx.y + di][threadIdx.x + dj];
                mu1 += ww * a; mu2 += ww * bb;
                xx += ww * a * a; yy += ww * bb * bb; xy += ww * a * bb;
            }
        }
        float s11 = xx - mu1 * mu1, s22 = yy - mu2 * mu2, s12 = xy - mu1 * mu2;
        const float C1 = 1e-4f, C2 = 9e-4f;
        val = ((2.0f * mu1 * mu2 + C1) * (2.0f * s12 + C2)) /
              ((mu1 * mu1 + mu2 * mu2 + C1) * (s11 + s22 + C2));
    }
    float tot = blockSum(val, tid);
    if (tid == 0) atomicAdd(&accB[b], tot);
}

// ---------------- gaussian smooth (9-tap sigma=1, symmetric pad), two passes ----------------
__device__ __forceinline__ int refl256(int i) { return i < 0 ? -1 - i : (i > 255 ? 511 - i : i); }

__device__ __forceinline__ void gauss9(float* w) {
    float s = 0.0f;
#pragma unroll
    for (int t = 0; t < 9; t++) { float d = (float)(t - 4); w[t] = expf(-0.5f * d * d); s += w[t]; }
    float inv = 1.0f / s;
#pragma unroll
    for (int t = 0; t < 9; t++) w[t] *= inv;
}

__global__ __launch_bounds__(256) void egf_smoothV(const float* __restrict__ y, float* __restrict__ tmp) {
    int g = blockIdx.x * 256 + threadIdx.x;      // < 393216
    int bc = g >> 16; int p = g & 65535; int i = p >> 8, j = p & 255;
    float w[9]; gauss9(w);
    const float* ip = y + bc * 65536;
    float s = 0.0f;
#pragma unroll
    for (int t = 0; t < 9; t++) s += w[t] * ip[(refl256(i + t - 4) << 8) + j];
    tmp[g] = s;
}

__global__ __launch_bounds__(256) void egf_smoothH(const float* __restrict__ tmp,
                                                   const float* __restrict__ y,
                                                   float* __restrict__ acc) {
    int g = blockIdx.x * 256 + threadIdx.x;
    int bc = g >> 16; int p = g & 65535; int i = p >> 8, j = p & 255;
    float w[9]; gauss9(w);
    const float* tp = tmp + bc * 65536;
    float s = 0.0f;
#pragma unroll
    for (int t = 0; t < 9; t++) s += w[t] * tp[(i << 8) + refl256(j + t - 4)];
    float d = s - y[g];
    float tt = blockSum(d * d, threadIdx.x);
    if (threadIdx.x == 0) atomicAdd(acc, tt);
}

// ---------------- gather masked point clouds ----------------
__global__ __launch_bounds__(256) void egf_gather(const float* __restrict__ y,
                                                  const float* __restrict__ pet,
                                                  const float* __restrict__ mask,
                                                  const int* __restrict__ idx,
                                                  float4* __restrict__ pts) {
    int t = blockIdx.x * 256 + threadIdx.x;      // < 8192
    int b = t >> 12, j = t & 4095;
    int p = idx[b * 4096 + j];
    float m = mask[b * 65536 + p];
    float a0 = y[(b * 3 + 0) * 65536 + p] * m;
    float a1 = y[(b * 3 + 1) * 65536 + p] * m;
    float a2 = y[(b * 3 + 2) * 65536 + p] * m;
    pts[(b * 2 + 0) * 4096 + j] = make_float4(a0, a1, a2, 0.5f * (a0 * a0 + a1 * a1 + a2 * a2));
    float c0 = pet[(b * 3 + 0) * 65536 + p] * m;
    float c1 = pet[(b * 3 + 1) * 65536 + p] * m;
    float c2 = pet[(b * 3 + 2) * 65536 + p] * m;
    pts[(b * 2 + 1) * 4096 + j] = make_float4(c0, c1, c2, 0.5f * (c0 * c0 + c1 * c1 + c2 * c2));
}

// ---------------- fused combine (staging) helper, NCH=64, float2 partials ----
// 4 threads per row (h = tid>>6), 16 chunk-partials each; coalesced 8B loads.
// Returns potential v for tid<64.
__device__ __forceinline__ float stageCombine(const float2* __restrict__ Pin,
                                              int qbase, int row, int h, int r_local,
                                              float* sm, float* ss, int tid) {
    const float2* p = Pin + qbase + (h * 16) * NPTS + row;
    float2 t[16];
#pragma unroll
    for (int k = 0; k < 16; k++) t[k] = p[k * NPTS];
    float m16 = -3.4e38f;
#pragma unroll
    for (int k = 0; k < 16; k++) m16 = fmaxf(m16, t[k].x);
    float s16 = 0.0f;
#pragma unroll
    for (int k = 0; k < 16; k++) s16 += t[k].y * __builtin_amdgcn_exp2f(t[k].x - m16);
    sm[h * 64 + r_local] = m16;
    ss[h * 64 + r_local] = s16;
    __syncthreads();
    float v = 0.0f;
    if (tid < 64) {
        float m0 = sm[tid], m1 = sm[64 + tid], m2 = sm[128 + tid], m3 = sm[192 + tid];
        float M = fmaxf(fmaxf(m0, m1), fmaxf(m2, m3));
        float S = ss[tid]       * __builtin_amdgcn_exp2f(m0 - M) +
                  ss[64 + tid]  * __builtin_amdgcn_exp2f(m1 - M) +
                  ss[128 + tid] * __builtin_amdgcn_exp2f(m2 - M) +
                  ss[192 + tid] * __builtin_amdgcn_exp2f(m3 - M);
        v = EPS_LOGN - EPS_LN2 * (M + log2f(S));
    }
    return v;
}

// ---------------- sinkhorn half: packed fp32 + op_sel broadcast, CHUNK=64 ----
// Rows staged as plain float4 {X,Y,Z,W} (K2-prescaled, W = (v-|p|^2/2)*K2):
// one ds_read_b128 per row per pass; broadcasts done inside VOP3P via op_sel.
// Stored partial m = max_r(a_r + dot) - b_c; b_c cancels in pass 2.
__global__ __launch_bounds__(256) void egf_sink_half8(const float4* __restrict__ pts,
                                                      const float2* __restrict__ Pin,
                                                      float2* __restrict__ Pout,
                                                      int dir, int init) {
    int q = blockIdx.z; int b = q / 3, t = q - b * 3;
    int xsel = (t == 2) ? 1 : 0;
    int ysel = (t == 1) ? 0 : 1;
    const float4* rowP = pts + (b * 2 + (dir ? ysel : xsel)) * NPTS;
    const float4* colP = pts + (b * 2 + (dir ? xsel : ysel)) * NPTS;

    __shared__ float4 srow[CHUNK];
    __shared__ float sm[256], ss[256];
    int tid = threadIdx.x;
    int chunk = blockIdx.y;
    int r_local = tid & 63, h = tid >> 6;
    int row = chunk * CHUNK + r_local;

    float v = 0.0f;
    if (!init)
        v = stageCombine(Pin, q * QSTRIDE, row, h, r_local, sm, ss, tid);
    if (tid < 64) {
        float4 pp = rowP[row];
        srow[tid] = make_float4(pp.x * INV_EPS_L2E, pp.y * INV_EPS_L2E,
                                pp.z * INV_EPS_L2E, (v - pp.w) * INV_EPS_L2E);
    }
    __syncthreads();

    int col0 = blockIdx.x * COLS_PER_BLK + tid;
    v2f cx[4], cy[4], cz[4], cw[4];
#pragma unroll
    for (int p = 0; p < 4; p++) {
        float4 c0 = colP[col0 + (2 * p) * 256];
        float4 c1 = colP[col0 + (2 * p + 1) * 256];
        cx[p] = (v2f){c0.x, c1.x};
        cy[p] = (v2f){c0.y, c1.y};
        cz[p] = (v2f){c0.z, c1.z};
        cw[p] = (v2f){c0.w * INV_EPS_L2E, c1.w * INV_EPS_L2E};
    }
    v2f mx[4];
#pragma unroll
    for (int p = 0; p < 4; p++) mx[p] = (v2f){-3.4e38f, -3.4e38f};
#pragma unroll 4
    for (int rr = 0; rr < CHUNK; rr++) {
        float4 rp = srow[rr];
        v2f rxy = (v2f){rp.x, rp.y};
        v2f rzw = (v2f){rp.z, rp.w};
#pragma unroll
        for (int p = 0; p < 4; p++) {
            v2f e = pk_fma_blo_chi(rzw, cz[p], rzw);   // Z*cz + W
            e = pk_fma_bhi(rxy, cy[p], e);             // + Y*cy
            e = pk_fma_blo(rxy, cx[p], e);             // + X*cx
            mx[p].x = fmaxf(mx[p].x, e.x);
            mx[p].y = fmaxf(mx[p].y, e.y);
        }
    }
    v2f mneg[4];
    float sax[4], say[4];
#pragma unroll
    for (int p = 0; p < 4; p++) { mneg[p] = -mx[p]; sax[p] = 0.0f; say[p] = 0.0f; }
#pragma unroll 4
    for (int rr = 0; rr < CHUNK; rr++) {
        float4 rp = srow[rr];
        v2f rxy = (v2f){rp.x, rp.y};
        v2f rzw = (v2f){rp.z, rp.w};
#pragma unroll
        for (int p = 0; p < 4; p++) {
            v2f e = pk_fma_blo(rzw, cz[p], mneg[p]);   // Z*cz - mx
            e = pk_fma_bhi(rxy, cy[p], e);             // + Y*cy
            e = pk_fma_blo(rxy, cx[p], e);             // + X*cx
            e = pk_add_bhi(e, rzw);                    // + W
            sax[p] += __builtin_amdgcn_exp2f(e.x);
            say[p] += __builtin_amdgcn_exp2f(e.y);
        }
    }
    float2* om = Pout + q * QSTRIDE + chunk * NPTS;
#pragma unroll
    for (int p = 0; p < 4; p++) {
        om[col0 + (2 * p) * 256]     = make_float2(mx[p].x - cw[p].x, sax[p]);
        om[col0 + (2 * p + 1) * 256] = make_float2(mx[p].y - cw[p].y, say[p]);
    }
}

// ---------------- sinkhorn value: f.mean() + g.mean() per problem ----------------
// grid (128, 6): blockIdx.x>>6 selects f/g partials, &63 selects the 64-row chunk.
__global__ __launch_bounds__(256) void egf_sink_val8(const float2* __restrict__ Pf,
                                                     const float2* __restrict__ Pg,
                                                     float* __restrict__ acc) {
    int q = blockIdx.y;
    int side = blockIdx.x >> 6;
    int chunk = blockIdx.x & 63;
    const float2* P = side ? Pg : Pf;
    __shared__ float sm[256], ss[256];
    int tid = threadIdx.x;
    int r_local = tid & 63, h = tid >> 6;
    int row = chunk * CHUNK + r_local;
    float v = stageCombine(P, q * QSTRIDE, row, h, r_local, sm, ss, tid);
    float tot = blockSum(v, tid);
    if (tid == 0) atomicAdd(&acc[A_SINK + q], tot * (1.0f / 4096.0f));
}

// ---------------- final scalar assembly ----------------
__global__ void egf_finalize(const float* __restrict__ acc, float* __restrict__ out) {
    if (threadIdx.x != 0 || blockIdx.x != 0) return;
    const float AREA = 246.0f * 246.0f;
    float ssim_m = 1.0f - (acc[A_SSIMA] + acc[A_SSIMA + 1]) / (2.0f * AREA);
    float ssim_p = 1.0f - (acc[A_SSIMB] + acc[A_SSIMB + 1]) / (2.0f * 3.0f * AREA);
    float g_cons = acc[A_CH1] / (2.0f * 65536.0f) + acc[A_CH2] / (2.0f * 16384.0f);
    float aux = acc[A_AUX] / (2.0f * 65536.0f);
    float inc0 = (acc[A_CNT]     >= 31.5f) ? 1.0f : 0.0f;
    float inc1 = (acc[A_CNT + 1] >= 31.5f) ? 1.0f : 0.0f;
    const float* v = acc + A_SINK;
    float Lt = (inc0 * (v[0] - 0.5f * v[1] - 0.5f * v[2]) +
                inc1 * (v[3] - 0.5f * v[4] - 0.5f * v[5])) * 0.5f;
    float Lo = (inc0 * acc[A_LOUT] + inc1 * acc[A_LOUT + 1]) / (3.0f * 65536.0f) * 0.5f;
    float Ls = (inc0 * (1.0f - acc[A_SSIMC] / (3.0f * AREA)) +
                inc1 * (1.0f - acc[A_SSIMC + 1] / (3.0f * AREA))) * 0.5f;
    float Li = 2.5f * acc[A_INT] / (2.0f * 3.0f * 65536.0f);
    float Lsm = acc[A_SMOOTH] / (2.0f * 3.0f * 65536.0f);
    float total = 0.8f * Lt + 0.3f * Lo + 0.5f * Ls + Li + 0.2f * Lsm;
    out[0] = total; out[1] = ssim_m; out[2] = ssim_p; out[3] = g_cons; out[4] = aux;
}

// ---------------- host launch ----------------
extern "C" void kernel_launch(void* const* d_in, const int* in_sizes, int n_in,
                              void* d_out, int out_size, void* d_ws, size_t ws_size,
                              hipStream_t stream) {
    const float* y    = (const float*)d_in[0];
    const float* mri  = (const float*)d_in[1];
    const float* pet  = (const float*)d_in[2];
    const float* mask = (const float*)d_in[3];
    const float* ehat = (const float*)d_in[4];
    const int*   idx  = (const int*)d_in[5];
    float* out = (float*)d_out;
    float* ws  = (float*)d_ws;

    float* acc   = ws;                    // 64 floats
    float4* pts  = (float4*)(ws + 64);    // 4*4096 float4 = 65536 floats
    float* base  = ws + 64 + 65536;

    // sinkhorn partials: 2 float2-planes of 6*64*4096 elements (12.6 MB apiece)
    float2* Pf = (float2*)base;
    float2* Pg = Pf + QSTRIDE * 6;
    float* ibase = base + 4 * QSTRIDE * 6;   // 2 planes * 2 floats/elem

    // image scratch
    float* ygray    = ibase;              // 131072
    float* py       = ygray + 131072;     // 32768
    float* pmri     = py + 32768;         // 32768
    float* mag_yg   = pmri + 32768;       // 131072
    float* mag_mri  = mag_yg + 131072;    // 131072
    float* mag_py   = mag_mri + 131072;   // 32768
    float* mag_pmri = mag_py + 32768;     // 32768
    float* tmp      = mag_pmri + 32768;   // 393216

    hipMemsetAsync(acc, 0, 64 * sizeof(float), stream);

    unsigned* mx = (unsigned*)(acc + A_MAX);

    egf_prep<<<dim3(256, 2), 256, 0, stream>>>(y, pet, mask, ygray, acc);
    egf_pool<<<dim3(64, 2), 256, 0, stream>>>(y, mri, py, pmri);
    egf_sobel<<<dim3(256, 2), 256, 0, stream>>>(ygray, mag_yg, mx + 0, 256, 8);
    egf_sobel<<<dim3(256, 2), 256, 0, stream>>>(mri, mag_mri, mx + 2, 256, 8);
    egf_sobel<<<dim3(64, 2), 256, 0, stream>>>(py, mag_py, mx + 4, 128, 7);
    egf_sobel<<<dim3(64, 2), 256, 0, stream>>>(pmri, mag_pmri, mx + 6, 128, 7);
    egf_charb<<<dim3(256, 2), 256, 0, stream>>>(mag_yg, mag_mri, mx + 0, mx + 2, ehat,
                                                acc + A_CH1, acc + A_AUX, 65536);
    egf_charb<<<dim3(64, 2), 256, 0, stream>>>(mag_py, mag_pmri, mx + 4, mx + 6, nullptr,
                                               acc + A_CH2, nullptr, 16384);
    egf_ssim<<<dim3(16, 16, 2), dim3(16, 16), 0, stream>>>(ygray, 65536, 0, mri, 65536, 0,
                                                           nullptr, 1, acc + A_SSIMA);
    egf_ssim<<<dim3(16, 16, 6), dim3(16, 16), 0, stream>>>(y, 196608, 65536, pet, 196608, 65536,
                                                           nullptr, 3, acc + A_SSIMB);
    egf_ssim<<<dim3(16, 16, 6), dim3(16, 16), 0, stream>>>(y, 196608, 65536, mri, 65536, 0,
                                                           mask, 3, acc + A_SSIMC);
    egf_smoothV<<<1536, 256, 0, stream>>>(y, tmp);
    egf_smoothH<<<1536, 256, 0, stream>>>(tmp, y, acc + A_SMOOTH);
    egf_gather<<<32, 256, 0, stream>>>(y, pet, mask, idx, pts);

    dim3 sgrid(NCB, NCH, 6);   // 2 x 64 x 6 = 768 blocks
    for (int it = 0; it < 11; ++it) {
        egf_sink_half8<<<sgrid, 256, 0, stream>>>(pts, Pf, Pg, 0, it == 0 ? 1 : 0);
        egf_sink_half8<<<sgrid, 256, 0, stream>>>(pts, Pg, Pf, 1, 0);
    }
    egf_sink_val8<<<dim3(128, 6), 256, 0, stream>>>(Pf, Pg, acc);
    egf_finalize<<<1, 64, 0, stream>>>(acc, out);
}

// Round 13
// 837.604 us; speedup vs baseline: 2.4660x; 1.0053x over previous
//
#include <hip/hip_runtime.h>
#include <math.h>

// ---------------- constants ----------------
#define INV_EPS_L2E 577.0780163555854f   // (1/eps) * log2(e) = 1/(eps*ln2)
#define EPS_LOGN 0.02079441542f          // eps * ln(4096) = -eps*loga
#define EPS_LN2 0.00173286795f           // eps * ln(2)

#define NPTS 4096
#define CHUNK 64
#define NCH 64            // 4096/64
#define CPT 8             // columns per thread (4 packed pairs)
#define COLS_PER_BLK 2048 // 256*CPT
#define NCB 2             // 4096/2048
#define QSTRIDE (NCH * NPTS)  // float2 elements per problem in partial arrays

typedef float v2f __attribute__((ext_vector_type(2)));

// True packed-fp32 ops with VOP3P op_sel broadcasts. gfx950 packed-f32 set is
// ONLY {v_pk_fma_f32, v_pk_mul_f32, v_pk_add_f32} — no v_pk_max_f32.
// op_sel[i] picks src-i half for LOW result lane; op_sel_hi[i] for HIGH.
__device__ __forceinline__ v2f pk_add(v2f a, v2f b) {
    v2f d;
    asm("v_pk_add_f32 %0, %1, %2" : "=v"(d) : "v"(a), "v"(b));
    return d;
}
// lo(a) broadcast to both lanes; b,c normal
__device__ __forceinline__ v2f pk_fma_blo(v2f a, v2f b, v2f c) {
    v2f d;
    asm("v_pk_fma_f32 %0, %1, %2, %3 op_sel:[0,0,0] op_sel_hi:[0,1,1]"
        : "=v"(d) : "v"(a), "v"(b), "v"(c));
    return d;
}
// hi(a) broadcast; b,c normal
__device__ __forceinline__ v2f pk_fma_bhi(v2f a, v2f b, v2f c) {
    v2f d;
    asm("v_pk_fma_f32 %0, %1, %2, %3 op_sel:[1,0,0] op_sel_hi:[1,1,1]"
        : "=v"(d) : "v"(a), "v"(b), "v"(c));
    return d;
}
// lo(a) broadcast AND hi(c) broadcast; b normal   (a.lo*b + c.hi per lane)
__device__ __forceinline__ v2f pk_fma_blo_chi(v2f a, v2f b, v2f c) {
    v2f d;
    asm("v_pk_fma_f32 %0, %1, %2, %3 op_sel:[0,0,1] op_sel_hi:[0,1,1]"
        : "=v"(d) : "v"(a), "v"(b), "v"(c));
    return d;
}
// a + hi(b) broadcast
__device__ __forceinline__ v2f pk_add_bhi(v2f a, v2f b) {
    v2f d;
    asm("v_pk_add_f32 %0, %1, %2 op_sel:[0,1] op_sel_hi:[1,1]"
        : "=v"(d) : "v"(a), "v"(b));
    return d;
}

// accumulator slots (floats) at start of workspace
constexpr int A_SSIMA  = 0;   // [B]
constexpr int A_SSIMB  = 2;   // [B]
constexpr int A_SSIMC  = 4;   // [B]
constexpr int A_CH1    = 6;
constexpr int A_CH2    = 7;
constexpr int A_AUX    = 8;
constexpr int A_INT    = 9;
constexpr int A_LOUT   = 10;  // [B]
constexpr int A_CNT    = 12;  // [B]
constexpr int A_SMOOTH = 14;
constexpr int A_SINK   = 16;  // [6]
constexpr int A_MAX    = 32;  // 8 uint slots (4 fields x B), float-bits

// ---------------- block reduction helpers (blockDim == 256) ----------------
__device__ __forceinline__ float blockSum(float v, int tid) {
#pragma unroll
    for (int o = 32; o; o >>= 1) v += __shfl_down(v, o, 64);
    __shared__ float sh[4];
    __syncthreads();
    if ((tid & 63) == 0) sh[tid >> 6] = v;
    __syncthreads();
    return sh[0] + sh[1] + sh[2] + sh[3];
}

__device__ __forceinline__ float blockMax(float v, int tid) {
#pragma unroll
    for (int o = 32; o; o >>= 1) v = fmaxf(v, __shfl_down(v, o, 64));
    __shared__ float sh[4];
    __syncthreads();
    if ((tid & 63) == 0) sh[tid >> 6] = v;
    __syncthreads();
    return fmaxf(fmaxf(sh[0], sh[1]), fmaxf(sh[2], sh[3]));
}

// ---------------- prep: y_gray, intensity, L_out, mask count ----------------
__global__ __launch_bounds__(256) void egf_prep(const float* __restrict__ y,
                                                const float* __restrict__ pet,
                                                const float* __restrict__ mask,
                                                float* __restrict__ ygray,
                                                float* __restrict__ acc) {
    int b = blockIdx.y;
    int p = blockIdx.x * 256 + threadIdx.x;      // exactly 65536
    float m  = mask[b * 65536 + p];
    float y0 = y[(b * 3 + 0) * 65536 + p];
    float y1 = y[(b * 3 + 1) * 65536 + p];
    float y2 = y[(b * 3 + 2) * 65536 + p];
    float q0 = pet[(b * 3 + 0) * 65536 + p];
    float q1 = pet[(b * 3 + 1) * 65536 + p];
    float q2 = pet[(b * 3 + 2) * 65536 + p];
    ygray[b * 65536 + p] = (y0 + y1 + y2) * (1.0f / 3.0f);
    float d0 = m * y0 - m * q0, d1 = m * y1 - m * q1, d2 = m * y2 - m * q2;
    float inten = d0 * d0 + d1 * d1 + d2 * d2;
    float im = 1.0f - m;
    float o0 = y0 * im, o1 = y1 * im, o2 = y2 * im;
    float lout = o0 * o0 + o1 * o1 + o2 * o2;
    float cnt = (m > 0.1f) ? 1.0f : 0.0f;
    float t;
    t = blockSum(inten, threadIdx.x); if (threadIdx.x == 0) atomicAdd(&acc[A_INT], t);
    t = blockSum(lout,  threadIdx.x); if (threadIdx.x == 0) atomicAdd(&acc[A_LOUT + b], t);
    t = blockSum(cnt,   threadIdx.x); if (threadIdx.x == 0) atomicAdd(&acc[A_CNT + b], t);
}

// ---------------- avgpool2 (y channel-mean, mri) ----------------
__global__ __launch_bounds__(256) void egf_pool(const float* __restrict__ y,
                                                const float* __restrict__ mri,
                                                float* __restrict__ py,
                                                float* __restrict__ pmri) {
    int b = blockIdx.y;
    int po = blockIdx.x * 256 + threadIdx.x;     // exactly 16384
    int i = po >> 7, j = po & 127;
    int p0 = (i * 2) * 256 + j * 2;
    float s = 0.0f;
#pragma unroll
    for (int c = 0; c < 3; c++) {
        const float* ip = y + (b * 3 + c) * 65536;
        s += ip[p0] + ip[p0 + 1] + ip[p0 + 256] + ip[p0 + 257];
    }
    py[b * 16384 + po] = s * (1.0f / 12.0f);
    const float* mp = mri + b * 65536;
    pmri[b * 16384 + po] = (mp[p0] + mp[p0 + 1] + mp[p0 + 256] + mp[p0 + 257]) * 0.25f;
}

// ---------------- sobel magnitude + per-sample max ----------------
__global__ __launch_bounds__(256) void egf_sobel(const float* __restrict__ in,
                                                 float* __restrict__ mag,
                                                 unsigned* __restrict__ mx,
                                                 int H, int logH) {
    int b = blockIdx.y;
    int p = blockIdx.x * 256 + threadIdx.x;
    int HH = H * H;
    const float* ip = in + b * HH;
    int i = p >> logH, j = p & (H - 1);
    auto at = [&](int ii, int jj) -> float {
        return (ii >= 0 && ii < H && jj >= 0 && jj < H) ? ip[(ii << logH) + jj] : 0.0f;
    };
    float a00 = at(i - 1, j - 1), a01 = at(i - 1, j), a02 = at(i - 1, j + 1);
    float a10 = at(i, j - 1),                         a12 = at(i, j + 1);
    float a20 = at(i + 1, j - 1), a21 = at(i + 1, j), a22 = at(i + 1, j + 1);
    float gx = a00 - a02 + 2.0f * a10 - 2.0f * a12 + a20 - a22;
    float gy = a00 + 2.0f * a01 + a02 - a20 - 2.0f * a21 - a22;
    float m = sqrtf(gx * gx + gy * gy + 1e-6f);
    mag[b * HH + p] = m;
    float bm = blockMax(m, threadIdx.x);
    if (threadIdx.x == 0) atomicMax(mx + b, __float_as_uint(bm));
}

// ---------------- charbonnier(+aux) over a normalized sobel pair ----------------
__global__ __launch_bounds__(256) void egf_charb(const float* __restrict__ magA,
                                                 const float* __restrict__ magB,
                                                 const unsigned* __restrict__ mxA,
                                                 const unsigned* __restrict__ mxB,
                                                 const float* __restrict__ ehat,
                                                 float* __restrict__ accC,
                                                 float* __restrict__ accAux,
                                                 int HH) {
    int b = blockIdx.y;
    int p = blockIdx.x * 256 + threadIdx.x;
    float c = 0.0f, au = 0.0f;
    float da = fmaxf(__uint_as_float(mxA[b]), 1e-6f);
    float db = fmaxf(__uint_as_float(mxB[b]), 1e-6f);
    if (p < HH) {
        float sa = magA[b * HH + p] / da;
        float sb = magB[b * HH + p] / db;
        float d = sa - sb;
        c = sqrtf(d * d + 1e-6f);
        if (ehat) au = fabsf(ehat[b * HH + p] - sb);
    }
    float tc = blockSum(c, threadIdx.x);
    if (threadIdx.x == 0) atomicAdd(accC, tc);
    if (ehat) {
        float ta = blockSum(au, threadIdx.x);
        if (threadIdx.x == 0) atomicAdd(accAux, ta);
    }
}

// ---------------- SSIM (11x11 gaussian, VALID -> 246x246), per-b sums ----------------
__global__ __launch_bounds__(256) void egf_ssim(const float* __restrict__ X, int xBS, int xCS,
                                                const float* __restrict__ Y, int yBS, int yCS,
                                                const float* __restrict__ M,
                                                int C_, float* __restrict__ accB) {
    int bc = blockIdx.z; int b = bc / C_; int c = bc - b * C_;
    const float* xp = X + b * xBS + c * xCS;
    const float* yp = Y + b * yBS + c * yCS;
    const float* mp = M ? (M + b * 65536) : nullptr;
    __shared__ float sx[26][27];
    __shared__ float sy[26][27];
    int ti = blockIdx.x * 16, tj = blockIdx.y * 16;
    int tid = threadIdx.y * 16 + threadIdx.x;
    for (int t = tid; t < 26 * 26; t += 256) {
        int li = t / 26, lj = t - li * 26;
        int gi = ti + li, gj = tj + lj;
        float a = 0.0f, bb = 0.0f;
        if (gi < 256 && gj < 256) {
            int p = (gi << 8) + gj;
            float m = mp ? mp[p] : 1.0f;
            a = xp[p] * m; bb = yp[p] * m;
        }
        sx[li][lj] = a; sy[li][lj] = bb;
    }
    __syncthreads();
    float w[11];
    {
        float s = 0.0f;
#pragma unroll
        for (int i = 0; i < 11; i++) { float d = (float)(i - 5); w[i] = expf(-d * d * (1.0f / 4.5f)); s += w[i]; }
        float inv = 1.0f / s;
#pragma unroll
        for (int i = 0; i < 11; i++) w[i] *= inv;
    }
    int oi = ti + threadIdx.y, oj = tj + threadIdx.x;
    float val = 0.0f;
    if (oi < 246 && oj < 246) {
        float mu1 = 0, mu2 = 0, xx = 0, yy = 0, xy = 0;
        for (int di = 0; di < 11; di++) {
            float wi = w[di];
#pragma unroll
            for (int dj = 0; dj < 11; dj++) {
                float ww = wi * w[dj];
                float a  = sx[threadIdx.y + di][threadIdx.x + dj];
                float bb = sy[threadIdx.y + di][threadIdx.x + dj];
                mu1 += ww * a; mu2 += ww * bb;
                xx += ww * a * a; yy += ww * bb * bb; xy += ww * a * bb;
            }
        }
        float s11 = xx - mu1 * mu1, s22 = yy - mu2 * mu2, s12 = xy - mu1 * mu2;
        const float C1 = 1e-4f, C2 = 9e-4f;
        val = ((2.0f * mu1 * mu2 + C1) * (2.0f * s12 + C2)) /
              ((mu1 * mu1 + mu2 * mu2 + C1) * (s11 + s22 + C2));
    }
    float tot = blockSum(val, tid);
    if (tid == 0) atomicAdd(&accB[b], tot);
}

// ---------------- gaussian smooth (9-tap sigma=1, symmetric pad), two passes ----------------
__device__ __forceinline__ int refl256(int i) { return i < 0 ? -1 - i : (i > 255 ? 511 - i : i); }

__device__ __forceinline__ void gauss9(float* w) {
    float s = 0.0f;
#pragma unroll
    for (int t = 0; t < 9; t++) { float d = (float)(t - 4); w[t] = expf(-0.5f * d * d); s += w[t]; }
    float inv = 1.0f / s;
#pragma unroll
    for (int t = 0; t < 9; t++) w[t] *= inv;
}

__global__ __launch_bounds__(256) void egf_smoothV(const float* __restrict__ y, float* __restrict__ tmp) {
    int g = blockIdx.x * 256 + threadIdx.x;      // < 393216
    int bc = g >> 16; int p = g & 65535; int i = p >> 8, j = p & 255;
    float w[9]; gauss9(w);
    const float* ip = y + bc * 65536;
    float s = 0.0f;
#pragma unroll
    for (int t = 0; t < 9; t++) s += w[t] * ip[(refl256(i + t - 4) << 8) + j];
    tmp[g] = s;
}

__global__ __launch_bounds__(256) void egf_smoothH(const float* __restrict__ tmp,
                                                   const float* __restrict__ y,
                                                   float* __restrict__ acc) {
    int g = blockIdx.x * 256 + threadIdx.x;
    int bc = g >> 16; int p = g & 65535; int i = p >> 8, j = p & 255;
    float w[9]; gauss9(w);
    const float* tp = tmp + bc * 65536;
    float s = 0.0f;
#pragma unroll
    for (int t = 0; t < 9; t++) s += w[t] * tp[(i << 8) + refl256(j + t - 4)];
    float d = s - y[g];
    float tt = blockSum(d * d, threadIdx.x);
    if (threadIdx.x == 0) atomicAdd(acc, tt);
}

// ---------------- gather masked point clouds ----------------
__global__ __launch_bounds__(256) void egf_gather(const float* __restrict__ y,
                                                  const float* __restrict__ pet,
                                                  const float* __restrict__ mask,
                                                  const int* __restrict__ idx,
                                                  float4* __restrict__ pts) {
    int t = blockIdx.x * 256 + threadIdx.x;      // < 8192
    int b = t >> 12, j = t & 4095;
    int p = idx[b * 4096 + j];
    float m = mask[b * 65536 + p];
    float a0 = y[(b * 3 + 0) * 65536 + p] * m;
    float a1 = y[(b * 3 + 1) * 65536 + p] * m;
    float a2 = y[(b * 3 + 2) * 65536 + p] * m;
    pts[(b * 2 + 0) * 4096 + j] = make_float4(a0, a1, a2, 0.5f * (a0 * a0 + a1 * a1 + a2 * a2));
    float c0 = pet[(b * 3 + 0) * 65536 + p] * m;
    float c1 = pet[(b * 3 + 1) * 65536 + p] * m;
    float c2 = pet[(b * 3 + 2) * 65536 + p] * m;
    pts[(b * 2 + 1) * 4096 + j] = make_float4(c0, c1, c2, 0.5f * (c0 * c0 + c1 * c1 + c2 * c2));
}

// ---------------- fused combine (staging) helper, NCH=64, float2 partials ----
// 4 threads per row (h = tid>>6), 16 chunk-partials each; coalesced 8B loads.
// Returns potential v for tid<64.
__device__ __forceinline__ float stageCombine(const float2* __restrict__ Pin,
                                              int qbase, int row, int h, int r_local,
                                              float* sm, float* ss, int tid) {
    const float2* p = Pin + qbase + (h * 16) * NPTS + row;
    float2 t[16];
#pragma unroll
    for (int k = 0; k < 16; k++) t[k] = p[k * NPTS];
    float m16 = -3.4e38f;
#pragma unroll
    for (int k = 0; k < 16; k++) m16 = fmaxf(m16, t[k].x);
    float s16 = 0.0f;
#pragma unroll
    for (int k = 0; k < 16; k++) s16 += t[k].y * __builtin_amdgcn_exp2f(t[k].x - m16);
    sm[h * 64 + r_local] = m16;
    ss[h * 64 + r_local] = s16;
    __syncthreads();
    float v = 0.0f;
    if (tid < 64) {
        float m0 = sm[tid], m1 = sm[64 + tid], m2 = sm[128 + tid], m3 = sm[192 + tid];
        float M = fmaxf(fmaxf(m0, m1), fmaxf(m2, m3));
        float S = ss[tid]       * __builtin_amdgcn_exp2f(m0 - M) +
                  ss[64 + tid]  * __builtin_amdgcn_exp2f(m1 - M) +
                  ss[128 + tid] * __builtin_amdgcn_exp2f(m2 - M) +
                  ss[192 + tid] * __builtin_amdgcn_exp2f(m3 - M);
        v = EPS_LOGN - EPS_LN2 * (M + log2f(S));
    }
    return v;
}

// ---------------- sinkhorn half: packed fp32 + op_sel broadcast, CHUNK=64 ----
// Rows staged as plain float4 {X,Y,Z,W} (K2-prescaled, W = (v-|p|^2/2)*K2):
// one ds_read_b128 per row per pass; broadcasts done inside VOP3P via op_sel.
// Column fragments prefetched before staging (vmcnt overlaps combine phase).
// Stored partial m = max_r(a_r + dot) - b_c; b_c cancels in pass 2.
__global__ __launch_bounds__(256) void egf_sink_half8(const float4* __restrict__ pts,
                                                      const float2* __restrict__ Pin,
                                                      float2* __restrict__ Pout,
                                                      int dir, int init) {
    int q = blockIdx.z; int b = q / 3, t = q - b * 3;
    int xsel = (t == 2) ? 1 : 0;
    int ysel = (t == 1) ? 0 : 1;
    const float4* rowP = pts + (b * 2 + (dir ? ysel : xsel)) * NPTS;
    const float4* colP = pts + (b * 2 + (dir ? xsel : ysel)) * NPTS;

    __shared__ float4 srow[CHUNK];
    __shared__ float sm[256], ss[256];
    int tid = threadIdx.x;
    int chunk = blockIdx.y;
    int r_local = tid & 63, h = tid >> 6;
    int row = chunk * CHUNK + r_local;

    // prefetch column fragments (independent of the staging barrier)
    int col0 = blockIdx.x * COLS_PER_BLK + tid;
    float4 cf[8];
#pragma unroll
    for (int k = 0; k < 8; k++) cf[k] = colP[col0 + k * 256];

    float v = 0.0f;
    if (!init)
        v = stageCombine(Pin, q * QSTRIDE, row, h, r_local, sm, ss, tid);
    if (tid < 64) {
        float4 pp = rowP[row];
        srow[tid] = make_float4(pp.x * INV_EPS_L2E, pp.y * INV_EPS_L2E,
                                pp.z * INV_EPS_L2E, (v - pp.w) * INV_EPS_L2E);
    }
    __syncthreads();

    v2f cx[4], cy[4], cz[4], cw[4];
#pragma unroll
    for (int p = 0; p < 4; p++) {
        cx[p] = (v2f){cf[2 * p].x, cf[2 * p + 1].x};
        cy[p] = (v2f){cf[2 * p].y, cf[2 * p + 1].y};
        cz[p] = (v2f){cf[2 * p].z, cf[2 * p + 1].z};
        cw[p] = (v2f){cf[2 * p].w * INV_EPS_L2E, cf[2 * p + 1].w * INV_EPS_L2E};
    }
    v2f mx[4];
#pragma unroll
    for (int p = 0; p < 4; p++) mx[p] = (v2f){-3.4e38f, -3.4e38f};
#pragma unroll 4
    for (int rr = 0; rr < CHUNK; rr++) {
        float4 rp = srow[rr];
        v2f rxy = (v2f){rp.x, rp.y};
        v2f rzw = (v2f){rp.z, rp.w};
#pragma unroll
        for (int p = 0; p < 4; p++) {
            v2f e = pk_fma_blo_chi(rzw, cz[p], rzw);   // Z*cz + W
            e = pk_fma_bhi(rxy, cy[p], e);             // + Y*cy
            e = pk_fma_blo(rxy, cx[p], e);             // + X*cx
            mx[p].x = fmaxf(mx[p].x, e.x);
            mx[p].y = fmaxf(mx[p].y, e.y);
        }
    }
    v2f mneg[4], sa[4];
#pragma unroll
    for (int p = 0; p < 4; p++) { mneg[p] = -mx[p]; sa[p] = (v2f){0.0f, 0.0f}; }
#pragma unroll 4
    for (int rr = 0; rr < CHUNK; rr++) {
        float4 rp = srow[rr];
        v2f rxy = (v2f){rp.x, rp.y};
        v2f rzw = (v2f){rp.z, rp.w};
#pragma unroll
        for (int p = 0; p < 4; p++) {
            v2f e = pk_fma_blo(rzw, cz[p], mneg[p]);   // Z*cz - mx
            e = pk_fma_bhi(rxy, cy[p], e);             // + Y*cy
            e = pk_fma_blo(rxy, cx[p], e);             // + X*cx
            e = pk_add_bhi(e, rzw);                    // + W
            v2f ex;
            ex.x = __builtin_amdgcn_exp2f(e.x);
            ex.y = __builtin_amdgcn_exp2f(e.y);
            sa[p] = pk_add(sa[p], ex);
        }
    }
    float2* om = Pout + q * QSTRIDE + chunk * NPTS;
#pragma unroll
    for (int p = 0; p < 4; p++) {
        om[col0 + (2 * p) * 256]     = make_float2(mx[p].x - cw[p].x, sa[p].x);
        om[col0 + (2 * p + 1) * 256] = make_float2(mx[p].y - cw[p].y, sa[p].y);
    }
}

// ---------------- sinkhorn value: f.mean() + g.mean() per problem ----------------
// grid (128, 6): blockIdx.x>>6 selects f/g partials, &63 selects the 64-row chunk.
__global__ __launch_bounds__(256) void egf_sink_val8(const float2* __restrict__ Pf,
                                                     const float2* __restrict__ Pg,
                                                     float* __restrict__ acc) {
    int q = blockIdx.y;
    int side = blockIdx.x >> 6;
    int chunk = blockIdx.x & 63;
    const float2* P = side ? Pg : Pf;
    __shared__ float sm[256], ss[256];
    int tid = threadIdx.x;
    int r_local = tid & 63, h = tid >> 6;
    int row = chunk * CHUNK + r_local;
    float v = stageCombine(P, q * QSTRIDE, row, h, r_local, sm, ss, tid);
    float tot = blockSum(v, tid);
    if (tid == 0) atomicAdd(&acc[A_SINK + q], tot * (1.0f / 4096.0f));
}

// ---------------- final scalar assembly ----------------
__global__ void egf_finalize(const float* __restrict__ acc, float* __restrict__ out) {
    if (threadIdx.x != 0 || blockIdx.x != 0) return;
    const float AREA = 246.0f * 246.0f;
    float ssim_m = 1.0f - (acc[A_SSIMA] + acc[A_SSIMA + 1]) / (2.0f * AREA);
    float ssim_p = 1.0f - (acc[A_SSIMB] + acc[A_SSIMB + 1]) / (2.0f * 3.0f * AREA);
    float g_cons = acc[A_CH1] / (2.0f * 65536.0f) + acc[A_CH2] / (2.0f * 16384.0f);
    float aux = acc[A_AUX] / (2.0f * 65536.0f);
    float inc0 = (acc[A_CNT]     >= 31.5f) ? 1.0f : 0.0f;
    float inc1 = (acc[A_CNT + 1] >= 31.5f) ? 1.0f : 0.0f;
    const float* v = acc + A_SINK;
    float Lt = (inc0 * (v[0] - 0.5f * v[1] - 0.5f * v[2]) +
                inc1 * (v[3] - 0.5f * v[4] - 0.5f * v[5])) * 0.5f;
    float Lo = (inc0 * acc[A_LOUT] + inc1 * acc[A_LOUT + 1]) / (3.0f * 65536.0f) * 0.5f;
    float Ls = (inc0 * (1.0f - acc[A_SSIMC] / (3.0f * AREA)) +
                inc1 * (1.0f - acc[A_SSIMC + 1] / (3.0f * AREA))) * 0.5f;
    float Li = 2.5f * acc[A_INT] / (2.0f * 3.0f * 65536.0f);
    float Lsm = acc[A_SMOOTH] / (2.0f * 3.0f * 65536.0f);
    float total = 0.8f * Lt + 0.3f * Lo + 0.5f * Ls + Li + 0.2f * Lsm;
    out[0] = total; out[1] = ssim_m; out[2] = ssim_p; out[3] = g_cons; out[4] = aux;
}

// ---------------- host launch ----------------
extern "C" void kernel_launch(void* const* d_in, const int* in_sizes, int n_in,
                              void* d_out, int out_size, void* d_ws, size_t ws_size,
                              hipStream_t stream) {
    const float* y    = (const float*)d_in[0];
    const float* mri  = (const float*)d_in[1];
    const float* pet  = (const float*)d_in[2];
    const float* mask = (const float*)d_in[3];
    const float* ehat = (const float*)d_in[4];
    const int*   idx  = (const int*)d_in[5];
    float* out = (float*)d_out;
    float* ws  = (float*)d_ws;

    float* acc   = ws;                    // 64 floats
    float4* pts  = (float4*)(ws + 64);    // 4*4096 float4 = 65536 floats
    float* base  = ws + 64 + 65536;

    // sinkhorn partials: 2 float2-planes of 6*64*4096 elements (12.6 MB apiece)
    float2* Pf = (float2*)base;
    float2* Pg = Pf + QSTRIDE * 6;
    float* ibase = base + 4 * QSTRIDE * 6;   // 2 planes * 2 floats/elem

    // image scratch
    float* ygray    = ibase;              // 131072
    float* py       = ygray + 131072;     // 32768
    float* pmri     = py + 32768;         // 32768
    float* mag_yg   = pmri + 32768;       // 131072
    float* mag_mri  = mag_yg + 131072;    // 131072
    float* mag_py   = mag_mri + 131072;   // 32768
    float* mag_pmri = mag_py + 32768;     // 32768
    float* tmp      = mag_pmri + 32768;   // 393216

    hipMemsetAsync(acc, 0, 64 * sizeof(float), stream);

    unsigned* mx = (unsigned*)(acc + A_MAX);

    egf_prep<<<dim3(256, 2), 256, 0, stream>>>(y, pet, mask, ygray, acc);
    egf_pool<<<dim3(64, 2), 256, 0, stream>>>(y, mri, py, pmri);
    egf_sobel<<<dim3(256, 2), 256, 0, stream>>>(ygray, mag_yg, mx + 0, 256, 8);
    egf_sobel<<<dim3(256, 2), 256, 0, stream>>>(mri, mag_mri, mx + 2, 256, 8);
    egf_sobel<<<dim3(64, 2), 256, 0, stream>>>(py, mag_py, mx + 4, 128, 7);
    egf_sobel<<<dim3(64, 2), 256, 0, stream>>>(pmri, mag_pmri, mx + 6, 128, 7);
    egf_charb<<<dim3(256, 2), 256, 0, stream>>>(mag_yg, mag_mri, mx + 0, mx + 2, ehat,
                                                acc + A_CH1, acc + A_AUX, 65536);
    egf_charb<<<dim3(64, 2), 256, 0, stream>>>(mag_py, mag_pmri, mx + 4, mx + 6, nullptr,
                                               acc + A_CH2, nullptr, 16384);
    egf_ssim<<<dim3(16, 16, 2), dim3(16, 16), 0, stream>>>(ygray, 65536, 0, mri, 65536, 0,
                                                           nullptr, 1, acc + A_SSIMA);
    egf_ssim<<<dim3(16, 16, 6), dim3(16, 16), 0, stream>>>(y, 196608, 65536, pet, 196608, 65536,
                                                           nullptr, 3, acc + A_SSIMB);
    egf_ssim<<<dim3(16, 16, 6), dim3(16, 16), 0, stream>>>(y, 196608, 65536, mri, 65536, 0,
                                                           mask, 3, acc + A_SSIMC);
    egf_smoothV<<<1536, 256, 0, stream>>>(y, tmp);
    egf_smoothH<<<1536, 256, 0, stream>>>(tmp, y, acc + A_SMOOTH);
    egf_gather<<<32, 256, 0, stream>>>(y, pet, mask, idx, pts);

    dim3 sgrid(NCB, NCH, 6);   // 2 x 64 x 6 = 768 blocks
    for (int it = 0; it < 11; ++it) {
        egf_sink_half8<<<sgrid, 256, 0, stream>>>(pts, Pf, Pg, 0, it == 0 ? 1 : 0);
        egf_sink_half8<<<sgrid, 256, 0, stream>>>(pts, Pg, Pf, 1, 0);
    }
    egf_sink_val8<<<dim3(128, 6), 256, 0, stream>>>(Pf, Pg, acc);
    egf_finalize<<<1, 64, 0, stream>>>(acc, out);
}